// Round 9
// baseline (430.011 us; speedup 1.0000x reference)
//
#include <hip/hip_runtime.h>

#define NN 50000
#define EE 600000
#define HH 128
#define TAU_INV 2.0f   // 1/TAU, TAU=0.5
#define PSZ 6250       // NN / 8 partitions (partition <-> XCD fixed bijection)
#define CAP 48         // bucket capacity; max degree for multinomial(600k,1/50k) ~ 36

// radix-fill parameters
#define BINB 512                         // bin_k blocks
#define BUFC 240                         // per-(role,part) LDS buffer cap per BLOCK
#define QCAP 80000                       // per-(role,part) queue cap (mean 75000, +19 sigma)
#define QPAD 16                          // qcnt stride (ints) -> one counter per 64B line
#define WSUB 32                          // sub-ranges per (role,partition)
#define SUBN 196                         // ceil(PSZ/WSUB)

typedef __attribute__((ext_vector_type(8))) short short8;
typedef __attribute__((ext_vector_type(4))) float f32x4;
typedef __attribute__((ext_vector_type(2))) float floatx2;

// ---------- helpers ----------
__device__ __forceinline__ float wsum64(float v) {
#pragma unroll
  for (int m = 32; m >= 1; m >>= 1) v += __shfl_xor(v, m, 64);
  return v;
}
__device__ __forceinline__ unsigned short f2bf(float f) {
  unsigned u = __builtin_bit_cast(unsigned, f);
  u = u + 0x7FFFu + ((u >> 16) & 1u);
  return (unsigned short)(u >> 16);
}
__device__ __forceinline__ float bf2f(unsigned short h) {
  unsigned u = ((unsigned)h) << 16;
  return __builtin_bit_cast(float, u);
}
// fp8 e4m3 (OCP) via gfx950 HW converts
__device__ __forceinline__ unsigned char fp8_enc1(float v) {
  int p = __builtin_amdgcn_cvt_pk_fp8_f32(v, v, 0, false);
  return (unsigned char)(p & 0xFF);
}
__device__ __forceinline__ void fp8x8_dec(uint2 v, float* f) {
  floatx2 a = __builtin_amdgcn_cvt_pk_f32_fp8(v.x, false);
  floatx2 b = __builtin_amdgcn_cvt_pk_f32_fp8(v.x, true);
  floatx2 c = __builtin_amdgcn_cvt_pk_f32_fp8(v.y, false);
  floatx2 d = __builtin_amdgcn_cvt_pk_f32_fp8(v.y, true);
  f[0] = a.x; f[1] = a.y; f[2] = b.x; f[3] = b.y;
  f[4] = c.x; f[5] = c.y; f[6] = d.x; f[7] = d.y;
}
__device__ __forceinline__ uint2 fp8x8_enc(const float* f) {
  int w0 = __builtin_amdgcn_cvt_pk_fp8_f32(f[0], f[1], 0, false);
  w0 = __builtin_amdgcn_cvt_pk_fp8_f32(f[2], f[3], w0, true);
  int w1 = __builtin_amdgcn_cvt_pk_fp8_f32(f[4], f[5], 0, false);
  w1 = __builtin_amdgcn_cvt_pk_fp8_f32(f[6], f[7], w1, true);
  return make_uint2((unsigned)w0, (unsigned)w1);
}

#define LDSW 136  // 128 + 8 bf16 pad

// ---------- phase 1: bin edges into (role x partition) queues ----------
// Reads each edge ONCE; grid-stride accumulation into LDS with no intermediate
// barriers; ONE global alloc atomic per (block,group); flattened prefix copy-out.
// Block 0 also does maskI setup (was derive_k's job).
// role 0: key=dst, pay=src (GCN)   role 1: key=he, pay=node   role 2: key=node, pay=he
__global__ __launch_bounds__(256) void bin_k(const int* __restrict__ ei,
                                             const int* __restrict__ ea,
                                             int* __restrict__ qcnt,
                                             unsigned int* __restrict__ qdata,
                                             const int* __restrict__ pos,
                                             const int* __restrict__ qp,
                                             int* __restrict__ maskI) {
  __shared__ int cnt[24], base[24], pfx[25];
  __shared__ unsigned int buf[24 * BUFC];
  const int tid = threadIdx.x;
  if (tid < 24) cnt[tid] = 0;
  if (blockIdx.x == 0 && tid < 100) maskI[pos[tid]] = 1;
  __syncthreads();
  if (blockIdx.x == 0 && tid == 0) maskI[*qp] = 0;
  for (int e = blockIdx.x * 256 + tid; e < EE; e += BINB * 256) {
    int pay0 = __builtin_nontemporal_load(ei + e);      // src
    int k0 = __builtin_nontemporal_load(ei + EE + e);   // dst
    int pay1 = __builtin_nontemporal_load(ea + e);      // node
    int k1 = __builtin_nontemporal_load(ea + EE + e);   // he
    int k2 = pay1, pay2 = k1;
    int g0 = k0 / PSZ;
    int g1 = 8 + k1 / PSZ;
    int g2 = 16 + k2 / PSZ;
    int o0 = atomicAdd(&cnt[g0], 1);
    int o1 = atomicAdd(&cnt[g1], 1);
    int o2 = atomicAdd(&cnt[g2], 1);
    if (o0 < BUFC) buf[g0 * BUFC + o0] = ((unsigned)k0 << 16) | (unsigned)pay0;
    if (o1 < BUFC) buf[g1 * BUFC + o1] = ((unsigned)k1 << 16) | (unsigned)pay1;
    if (o2 < BUFC) buf[g2 * BUFC + o2] = ((unsigned)k2 << 16) | (unsigned)pay2;
  }
  __syncthreads();
  if (tid < 24) {
    int c = min(cnt[tid], BUFC);
    cnt[tid] = c;
    base[tid] = atomicAdd(&qcnt[tid * QPAD], c);  // padded: 1 counter per 64B line
  }
  __syncthreads();
  if (tid == 0) {
    int s = 0;
#pragma unroll
    for (int g = 0; g < 24; ++g) { pfx[g] = s; s += cnt[g]; }
    pfx[24] = s;
  }
  __syncthreads();
  const int total = pfx[24];
  for (int j = tid; j < total; j += 256) {
    int lo2 = 0, hi2 = 24;
    while (lo2 + 1 < hi2) {
      int mid = (lo2 + hi2) >> 1;
      if (j >= pfx[mid]) lo2 = mid; else hi2 = mid;
    }
    int g = lo2;
    int i = j - pfx[g];
    int dq = base[g] + i;
    if (dq < QCAP) qdata[(size_t)g * QCAP + dq] = buf[g * BUFC + i];
  }
}

// ---------- phase 2: partitioned fill with LDS cursors (+ fused derive) ----------
// wg w: partition p = w&7 (== XCD id, queue L2-local), role r, sub-range s.
// Role-specific degree vector written at cursor writeback (derive_k folded in).
__global__ __launch_bounds__(256) void fillp_k(const int* __restrict__ qcnt,
                                               const unsigned int* __restrict__ qdata,
                                               int* __restrict__ cursor,
                                               unsigned short* __restrict__ slotsA,
                                               unsigned short* __restrict__ slotsB,
                                               unsigned short* __restrict__ slotsC,
                                               float* __restrict__ cntq,
                                               const int* __restrict__ qp,
                                               float* __restrict__ dinv,
                                               float* __restrict__ Binv,
                                               float* __restrict__ Dninv) {
  __shared__ int cur[SUBN];
  const int w = blockIdx.x;  // 0..767
  const int p = w & 7;
  const int r = (w >> 3) % 3;
  const int s = w / 24;
  const int lo = p * PSZ + s * SUBN;
  const int hi = min(lo + SUBN, (p + 1) * PSZ);
  const int tid = threadIdx.x;
  if (tid < SUBN) cur[tid] = 0;
  __syncthreads();
  const int g = r * 8 + p;
  const int qlen = min(qcnt[g * QPAD], QCAP);
  const unsigned int* qd = qdata + (size_t)g * QCAP;
  unsigned short* slots = (r == 0) ? slotsA : (r == 1) ? slotsB : slotsC;
  const int q = *qp;
  auto proc = [&](unsigned int rec) {
    int key = (int)(rec >> 16);
    if (key >= lo && key < hi) {
      int pay = (int)(rec & 0xFFFFu);
      int idx = atomicAdd(&cur[key - lo], 1);
      if (idx < CAP) slots[key * CAP + idx] = (unsigned short)pay;
      if (r == 1 && pay == q) atomicAdd(&cntq[key], 1.0f);
    }
  };
  const int nv4 = qlen >> 2;
  const uint4* qd4 = (const uint4*)qd;
  int j = tid;
  for (; j + 256 < nv4; j += 512) {
    uint4 r0 = qd4[j];
    uint4 r1 = qd4[j + 256];
    proc(r0.x); proc(r0.y); proc(r0.z); proc(r0.w);
    proc(r1.x); proc(r1.y); proc(r1.z); proc(r1.w);
  }
  if (j < nv4) {
    uint4 r0 = qd4[j];
    proc(r0.x); proc(r0.y); proc(r0.z); proc(r0.w);
  }
  int i = (nv4 << 2) + tid;
  if (i < qlen) proc(qd[i]);
  __syncthreads();
  for (int k = lo + tid; k < hi; k += 256) {
    int c = cur[k - lo];
    cursor[r * NN + k] = c;
    if (r == 0) dinv[k] = rsqrtf((float)(c + 1));            // deg incl. self-loop
    else if (r == 1) Binv[k] = (c > 0) ? 1.0f / (float)c : 0.0f;
    else Dninv[k] = (c > 0) ? 1.0f / (float)c : 0.0f;
  }
}

// ---------- shq body: analytic query coefficients ----------
__device__ __forceinline__ void shq_body(const int* __restrict__ ei, const int* __restrict__ ea,
                                         const int* __restrict__ qp,
                                         const float* __restrict__ dinv,
                                         const float* __restrict__ Binv,
                                         const float* __restrict__ cntq,
                                         float* __restrict__ s_hq, float* __restrict__ s_hgq,
                                         int bid) {
  int e = bid * 256 + threadIdx.x;
  if (e >= EE) return;
  int q = *qp;
  int src = __builtin_nontemporal_load(ei + e);
  if (src == q) {
    int dst = __builtin_nontemporal_load(ei + EE + e);
    atomicAdd(&s_hq[dst], dinv[q] * dinv[dst]);
  }
  int he = __builtin_nontemporal_load(ea + EE + e);
  float cq = cntq[he];
  if (cq != 0.0f) {
    int node = __builtin_nontemporal_load(ea + e);
    atomicAdd(&s_hgq[node], Binv[he] * cq);
  }
  if (e == 0) atomicAdd(&s_hq[q], dinv[q] * dinv[q]);  // self-loop of query gcn
}

// ---------- fuse2 body: hf_ and hfh_ from analytic querys2 and feats2(bf16) ----------
__device__ __forceinline__ void fuse2_body(const unsigned short* __restrict__ f2,
                                           const int* __restrict__ qp,
                                           const float* __restrict__ Wlq,
                                           const float* __restrict__ blq,
                                           const float* __restrict__ aq1,
                                           const float* __restrict__ a1,
                                           const float* __restrict__ aq2,
                                           const float* __restrict__ a2,
                                           unsigned short* __restrict__ out1,
                                           unsigned short* __restrict__ out2, int bid) {
  int row = bid * 4 + (threadIdx.x >> 6);
  if (row >= NN) return;
  int lane = threadIdx.x & 63;
  int c0 = lane, c1 = lane + 64;
  int q = *qp;
  float q20 = blq[c0] + ((row == q) ? Wlq[c0] : 0.f);
  float q21 = blq[c1] + ((row == q) ? Wlq[c1] : 0.f);
  float f0 = bf2f(f2[(size_t)row * 128 + c0]);
  float f1 = bf2f(f2[(size_t)row * 128 + c1]);
  float dq1 = wsum64(q20 * aq1[c0] + q21 * aq1[c1]);
  float df1 = wsum64(f0 * a1[c0] + f1 * a1[c1]);
  float dq2 = wsum64(q20 * aq2[c0] + q21 * aq2[c1]);
  float df2 = wsum64(f0 * a2[c0] + f1 * a2[c1]);
  {
    float mx = fmaxf(dq1, df1);
    float e0 = expf(dq1 - mx), e1 = expf(df1 - mx);
    float w0 = e0 / (e0 + e1), w1 = 1.f - w0;
    out1[(size_t)row * 128 + c0] = f2bf(w0 * q20 + w1 * f0);
    out1[(size_t)row * 128 + c1] = f2bf(w0 * q21 + w1 * f1);
  }
  {
    float mx = fmaxf(dq2, df2);
    float e0 = expf(dq2 - mx), e1 = expf(df2 - mx);
    float w0 = e0 / (e0 + e1), w1 = 1.f - w0;
    out2[(size_t)row * 128 + c0] = f2bf(w0 * q20 + w1 * f0);
    out2[(size_t)row * 128 + c1] = f2bf(w0 * q21 + w1 * f1);
  }
}

// ---------- fused f2: {shq | fuse2} ----------
__global__ __launch_bounds__(256) void f2_k(const int* __restrict__ ei,
                                            const int* __restrict__ ea,
                                            const int* __restrict__ qp,
                                            const float* __restrict__ dinv,
                                            const float* __restrict__ Binv,
                                            const float* __restrict__ cntq,
                                            float* __restrict__ s_hq,
                                            float* __restrict__ s_hgq,
                                            const unsigned short* __restrict__ B6,
                                            const float* __restrict__ Wlq,
                                            const float* __restrict__ blq,
                                            const float* __restrict__ aq_,
                                            const float* __restrict__ a_,
                                            const float* __restrict__ ahq_,
                                            const float* __restrict__ ah_,
                                            unsigned short* __restrict__ B3,
                                            unsigned short* __restrict__ B4, int eb) {
  int b = blockIdx.x;
  if (b < eb)
    shq_body(ei, ea, qp, dinv, Binv, cntq, s_hq, s_hgq, b);
  else
    fuse2_body(B6, qp, Wlq, blq, aq_, a_, ahq_, ah_, B3, B4, b - eb);
}

// ---------- pack 7 weight matrices into MFMA B-fragment order ----------
__global__ void pack_k(const float* __restrict__ W0, const float* __restrict__ Wh0,
                       const float* __restrict__ Wlf, const float* __restrict__ Wf0,
                       const float* __restrict__ Wfh0, const float* __restrict__ Wm1,
                       const float* __restrict__ Wm2, unsigned short* __restrict__ out) {
  int tid = blockIdx.x * 256 + threadIdx.x;
  if (tid >= 7 * 2048) return;
  int mat = tid >> 11, r = tid & 2047;
  int s = r >> 9, c = (r >> 6) & 7, lane = r & 63;
  const float* W = (mat == 0) ? W0 : (mat == 1) ? Wh0 : (mat == 2) ? Wlf
                 : (mat == 3) ? Wf0 : (mat == 4) ? Wfh0 : (mat == 5) ? Wm1 : Wm2;
  int k0 = 32 * s + (lane >> 4) * 8;
  int n = 16 * c + (lane & 15);
  unsigned short* o = out + (size_t)tid * 8;
#pragma unroll
  for (int j = 0; j < 8; ++j) o[j] = f2bf(W[(k0 + j) * 128 + n]);
}

// ---------- gemm core (A staged in LDS as bf16; LDS-staged coalesced epilogue) ----------
// OM: 1 = bf16 out (ushort stride 128), 2 = fp8 out (uchar stride 256).
template <bool BIAS, bool RELU, int OM>
__device__ __forceinline__ void gemm_core(unsigned short* As, const short8* Wp,
                                          const float* bias, void* outv, int r0, int nrows,
                                          int tid) {
  const int wave = tid >> 6, lane = tid & 63;
  const int quad = lane >> 4, l15 = lane & 15;
  f32x4 acc[8];
#pragma unroll
  for (int c = 0; c < 8; ++c) acc[c] = (f32x4){0.f, 0.f, 0.f, 0.f};
#pragma unroll
  for (int s = 0; s < 4; ++s) {
    short8 a = *(const short8*)&As[(wave * 16 + l15) * LDSW + s * 32 + quad * 8];
#pragma unroll
    for (int c = 0; c < 8; ++c) {
      short8 b = Wp[(s * 8 + c) * 64 + lane];
      acc[c] = __builtin_amdgcn_mfma_f32_16x16x32_bf16(a, b, acc[c], 0, 0, 0);
    }
  }
  __syncthreads();  // all waves done reading As before overwrite
  const int rwl = wave * 16 + quad * 4;  // local row base
  if (OM == 2) {
    unsigned char* l8 = (unsigned char*)As;  // [64][128] fp8 = 8KB
#pragma unroll
    for (int c = 0; c < 8; ++c) {
      int col = c * 16 + l15;
      float bv = BIAS ? bias[col] : 0.f;
#pragma unroll
      for (int r = 0; r < 4; ++r) {
        float v = acc[c][r] + bv;
        if (RELU) v = fmaxf(v, 0.f);
        l8[(rwl + r) * 128 + col] = fp8_enc1(v);
      }
    }
    __syncthreads();
#pragma unroll
    for (int t = 0; t < 2; ++t) {
      int idx = (t * 256 + tid) * 16;  // 0..8191
      int row = idx >> 7, off = idx & 127;
      int grow = r0 + row;
      if (grow < nrows)
        *(uint4*)&((unsigned char*)outv)[(size_t)grow * 256 + off] = *(uint4*)&l8[idx];
    }
  } else {
    unsigned short* l16 = As;  // [64][128] ushort = 16KB
#pragma unroll
    for (int c = 0; c < 8; ++c) {
      int col = c * 16 + l15;
      float bv = BIAS ? bias[col] : 0.f;
#pragma unroll
      for (int r = 0; r < 4; ++r) {
        float v = acc[c][r] + bv;
        if (RELU) v = fmaxf(v, 0.f);
        l16[(rwl + r) * 128 + col] = f2bf(v);
      }
    }
    __syncthreads();
#pragma unroll
    for (int t = 0; t < 4; ++t) {
      int idx = (t * 256 + tid) * 16;  // byte idx 0..16383
      int row = idx >> 8, off = idx & 255;
      int grow = r0 + row;
      if (grow < nrows)
        *(uint4*)&((unsigned char*)outv)[(size_t)grow * 256 + off] =
            *(uint4*)&((unsigned char*)l16)[idx];
    }
  }
}

__device__ __forceinline__ void stage_bf16(const unsigned short* A, unsigned short* As,
                                           int r0, int nrows, int tid) {
#pragma unroll
  for (int t = 0; t < 4; ++t) {
    int v = t * 256 + tid;
    int row = v >> 4, cc = v & 15;
    int gr = r0 + row;
    uint4 val = make_uint4(0, 0, 0, 0);
    if (gr < nrows) val = ((const uint4*)A)[(size_t)gr * 16 + cc];
    *(uint4*)&As[row * LDSW + cc * 8] = val;
  }
}

// ---------- batched pair GEMM: two independent A@W ----------
template <bool BIAS, bool RELU, int OM>
__global__ __launch_bounds__(256) void gemm2_mfma(const unsigned short* __restrict__ A0,
                                                  const unsigned short* __restrict__ A1,
                                                  const short8* __restrict__ Wp0,
                                                  const short8* __restrict__ Wp1,
                                                  const float* __restrict__ b0,
                                                  const float* __restrict__ b1,
                                                  void* __restrict__ o0, void* __restrict__ o1,
                                                  int nrows, int nblk) {
  __shared__ unsigned short As[64 * LDSW];
  int b = blockIdx.x;
  const unsigned short* A = A0;
  const short8* Wp = Wp0;
  const float* bias = b0;
  void* o = o0;
  if (b >= nblk) {
    b -= nblk; A = A1; Wp = Wp1; bias = b1; o = o1;
  }
  const int r0 = b * 64;
  stage_bf16(A, As, r0, nrows, threadIdx.x);
  __syncthreads();
  gemm_core<BIAS, RELU, OM>(As, Wp, bias, o, r0, nrows, threadIdx.x);
}

// ---------- 3 GEMMs sharing one fp32-A tile; column-halved for occupancy ----------
__global__ __launch_bounds__(256) void gemm3_mfma(const float* __restrict__ A,
                                                  const short8* __restrict__ Wp,  // mats 0,1,2
                                                  const float* __restrict__ bias2,
                                                  unsigned char* __restrict__ p1,
                                                  unsigned char* __restrict__ p2,
                                                  unsigned short* __restrict__ out2,
                                                  int nrows) {
  __shared__ unsigned short As[64 * LDSW];
  const int tid = threadIdx.x;
  const int bh = blockIdx.x & 1;
  const int r0 = (blockIdx.x >> 1) * 64;
#pragma unroll
  for (int t = 0; t < 8; ++t) {
    int v = t * 256 + tid;
    int row = v >> 5, c4 = v & 31;  // float4 chunk
    int gr = r0 + row;
    f32x4 val = (f32x4){0.f, 0.f, 0.f, 0.f};
    if (gr < nrows) val = ((const f32x4*)A)[(size_t)gr * 32 + c4];  // plain: L3 reuse
    ushort4 o;
    o.x = f2bf(val.x); o.y = f2bf(val.y); o.z = f2bf(val.z); o.w = f2bf(val.w);
    *(ushort4*)&As[row * LDSW + c4 * 4] = o;
  }
  __syncthreads();
  const int wave = tid >> 6, lane = tid & 63;
  const int quad = lane >> 4, l15 = lane & 15;
  f32x4 acc[3][4];
#pragma unroll
  for (int m = 0; m < 3; ++m)
#pragma unroll
    for (int c = 0; c < 4; ++c) acc[m][c] = (f32x4){0.f, 0.f, 0.f, 0.f};
#pragma unroll
  for (int s = 0; s < 4; ++s) {
    short8 a = *(const short8*)&As[(wave * 16 + l15) * LDSW + s * 32 + quad * 8];
#pragma unroll
    for (int m = 0; m < 3; ++m)
#pragma unroll
      for (int c = 0; c < 4; ++c) {
        short8 bb = Wp[(size_t)m * 2048 + (s * 8 + bh * 4 + c) * 64 + lane];
        acc[m][c] = __builtin_amdgcn_mfma_f32_16x16x32_bf16(a, bb, acc[m][c], 0, 0, 0);
      }
  }
  __syncthreads();  // done reading As
  // stage outputs: P1 [64][64]B @0, P2 @4096, B6 [64][64]ushort @8192 (16KB total)
  unsigned char* l8a = (unsigned char*)As;
  unsigned char* l8b = l8a + 4096;
  unsigned short* l16 = (unsigned short*)(l8a + 8192);
  const int rwl = wave * 16 + quad * 4;
#pragma unroll
  for (int c = 0; c < 4; ++c) {
    int coll = c * 16 + l15;                 // local col 0..63
    float bv = bias2[(bh * 4 + c) * 16 + l15];
#pragma unroll
    for (int r = 0; r < 4; ++r) {
      int lrow = rwl + r;
      l8a[lrow * 64 + coll] = fp8_enc1(acc[0][c][r]);
      l8b[lrow * 64 + coll] = fp8_enc1(acc[1][c][r]);
      l16[lrow * 64 + coll] = f2bf(acc[2][c][r] + bv);
    }
  }
  __syncthreads();
  {  // P1/P2: 4KB each, 16B per thread, rows are 64B-contiguous chunks
    int idx = tid * 16;
    int row = idx >> 6, off = idx & 63;
    int grow = r0 + row;
    if (grow < nrows) {
      *(uint4*)&p1[(size_t)grow * 256 + bh * 64 + off] = *(uint4*)&l8a[idx];
      *(uint4*)&p2[(size_t)grow * 256 + bh * 64 + off] = *(uint4*)&l8b[idx];
    }
  }
#pragma unroll
  for (int t = 0; t < 2; ++t) {  // B6: 8KB, rows are 128B-contiguous chunks
    int idx = (t * 256 + tid) * 16;
    int row = idx >> 7, off = idx & 127;
    int grow = r0 + row;
    if (grow < nrows)
      *(uint4*)&((unsigned char*)out2)[(size_t)grow * 256 + bh * 128 + off] =
          *(uint4*)&((unsigned char*)l16)[idx];
  }
}

// ---------- paired gather (bucket CSR), fp8-pair input ----------
// Wave64 = ONE node; two 32-lane halves process even/odd neighbors of the SAME node
// (no cross-half degree divergence — was ~15% masked-iteration waste), up to 4 row
// loads in flight per lane; half-accumulators merged via shfl_xor(32).
// MODE 0: y[i] = wv[i]*(wv[i]*x[i] + sum_s wv[s]*x[s])   (GCN w/ self-loop)
// MODE 1: y[i] = wv[i]*sum_s x[s]                         (hypergraph halves)
template <int MODE, bool OUTFP8>
__device__ __forceinline__ void gpair_body(const uint2* __restrict__ xp,
                                           unsigned short* __restrict__ y1,
                                           unsigned short* __restrict__ y2,
                                           uint2* __restrict__ yp,
                                           const int* __restrict__ cnt,
                                           const unsigned short* __restrict__ slots,
                                           const float* __restrict__ wv, int blk) {
  int node = blk * 4 + (threadIdx.x >> 6);
  if (node >= NN) return;
  const int lane = threadIdx.x & 63;
  const int l = lane & 31;
  const int h = lane >> 5;  // neighbor parity for this half
  const int st = node * CAP;
  const int n = min(cnt[node], CAP);
  float acc[8];
#pragma unroll
  for (int i = 0; i < 8; ++i) acc[i] = 0.f;
  int j = h;
  // main: 4 neighbors per lane (8 per wave) with 4 row loads in flight
  for (; j + 6 < n; j += 8) {
    int s0 = slots[st + j];
    int s1 = slots[st + j + 2];
    int s2 = slots[st + j + 4];
    int s3 = slots[st + j + 6];
    uint2 v0 = xp[(size_t)s0 * 32 + l];
    uint2 v1 = xp[(size_t)s1 * 32 + l];
    uint2 v2 = xp[(size_t)s2 * 32 + l];
    uint2 v3 = xp[(size_t)s3 * 32 + l];
    float f[8];
    if (MODE == 0) {
      float w0 = wv[s0], w1 = wv[s1], w2 = wv[s2], w3 = wv[s3];
      fp8x8_dec(v0, f);
#pragma unroll
      for (int i = 0; i < 8; ++i) acc[i] = fmaf(w0, f[i], acc[i]);
      fp8x8_dec(v1, f);
#pragma unroll
      for (int i = 0; i < 8; ++i) acc[i] = fmaf(w1, f[i], acc[i]);
      fp8x8_dec(v2, f);
#pragma unroll
      for (int i = 0; i < 8; ++i) acc[i] = fmaf(w2, f[i], acc[i]);
      fp8x8_dec(v3, f);
#pragma unroll
      for (int i = 0; i < 8; ++i) acc[i] = fmaf(w3, f[i], acc[i]);
    } else {
      fp8x8_dec(v0, f);
#pragma unroll
      for (int i = 0; i < 8; ++i) acc[i] += f[i];
      fp8x8_dec(v1, f);
#pragma unroll
      for (int i = 0; i < 8; ++i) acc[i] += f[i];
      fp8x8_dec(v2, f);
#pragma unroll
      for (int i = 0; i < 8; ++i) acc[i] += f[i];
      fp8x8_dec(v3, f);
#pragma unroll
      for (int i = 0; i < 8; ++i) acc[i] += f[i];
    }
  }
  // 2-wide tail
  for (; j + 2 < n; j += 4) {
    int s0 = slots[st + j];
    int s1 = slots[st + j + 2];
    uint2 v0 = xp[(size_t)s0 * 32 + l];
    uint2 v1 = xp[(size_t)s1 * 32 + l];
    float f[8];
    if (MODE == 0) {
      float w0 = wv[s0], w1 = wv[s1];
      fp8x8_dec(v0, f);
#pragma unroll
      for (int i = 0; i < 8; ++i) acc[i] = fmaf(w0, f[i], acc[i]);
      fp8x8_dec(v1, f);
#pragma unroll
      for (int i = 0; i < 8; ++i) acc[i] = fmaf(w1, f[i], acc[i]);
    } else {
      fp8x8_dec(v0, f);
#pragma unroll
      for (int i = 0; i < 8; ++i) acc[i] += f[i];
      fp8x8_dec(v1, f);
#pragma unroll
      for (int i = 0; i < 8; ++i) acc[i] += f[i];
    }
  }
  // single tail
  if (j < n) {
    int s0 = slots[st + j];
    uint2 v0 = xp[(size_t)s0 * 32 + l];
    float f[8];
    fp8x8_dec(v0, f);
    if (MODE == 0) {
      float w0 = wv[s0];
#pragma unroll
      for (int i = 0; i < 8; ++i) acc[i] = fmaf(w0, f[i], acc[i]);
    } else {
#pragma unroll
      for (int i = 0; i < 8; ++i) acc[i] += f[i];
    }
  }
  // merge the two halves (lane l and lane l+32 hold partial sums of same elements)
#pragma unroll
  for (int i = 0; i < 8; ++i) acc[i] += __shfl_xor(acc[i], 32, 64);
  float sc = wv[node];
  if (MODE == 0) {
    uint2 v = xp[(size_t)node * 32 + l];
    float f[8];
    fp8x8_dec(v, f);
#pragma unroll
    for (int i = 0; i < 8; ++i) acc[i] = sc * fmaf(sc, f[i], acc[i]);
  } else {
#pragma unroll
    for (int i = 0; i < 8; ++i) acc[i] *= sc;
  }
  if (h == 0) {  // both halves hold identical merged values; half 0 stores
    if (OUTFP8) {
      yp[(size_t)node * 32 + l] = fp8x8_enc(acc);
    } else {
      unsigned short* y = (l < 16) ? y1 : y2;
      int cg = l & 15;
      uint4 o;
      o.x = ((unsigned)f2bf(acc[1]) << 16) | f2bf(acc[0]);
      o.y = ((unsigned)f2bf(acc[3]) << 16) | f2bf(acc[2]);
      o.z = ((unsigned)f2bf(acc[5]) << 16) | f2bf(acc[4]);
      o.w = ((unsigned)f2bf(acc[7]) << 16) | f2bf(acc[6]);
      *(uint4*)&y[(size_t)node * 128 + cg * 8] = o;
    }
  }
}

// merged: pass1 (GCN, MODE0, slotsA, bf16 outs) + pass2 (HG-he, MODE1, slotsB, fp8-pair out)
__global__ void dgather12_k(const uint2* __restrict__ xp1, unsigned short* __restrict__ y1a,
                            unsigned short* __restrict__ y1b, const uint2* __restrict__ xp2,
                            uint2* __restrict__ yp3, const int* __restrict__ cursor,
                            const unsigned short* __restrict__ slotsA,
                            const unsigned short* __restrict__ slotsB,
                            const float* __restrict__ dinv, const float* __restrict__ Binv,
                            int nblk) {
  int b = blockIdx.x;
  if (b < nblk)
    gpair_body<0, false>(xp1, y1a, y1b, nullptr, cursor, slotsA, dinv, b);
  else
    gpair_body<1, true>(xp2, nullptr, nullptr, yp3, cursor + NN, slotsB, Binv, b - nblk);
}

__global__ void dgather3_k(const uint2* __restrict__ xp, unsigned short* __restrict__ y1,
                           unsigned short* __restrict__ y2, const int* __restrict__ cursor,
                           const unsigned short* __restrict__ slotsC,
                           const float* __restrict__ wv) {
  gpair_body<1, false>(xp, y1, y2, nullptr, cursor + 2 * NN, slotsC, wv, blockIdx.x);
}

// ---------- fused: fuse(analytic-query, conv) + residual + relu -> bf16 (batched x2) -----
__device__ __forceinline__ void fuse_add_body(const unsigned short* __restrict__ g,
                                              const unsigned short* __restrict__ gr,
                                              const float* __restrict__ svec,
                                              const float* __restrict__ dscale,
                                              const float* __restrict__ Wq,
                                              const float* __restrict__ bq,
                                              const float* __restrict__ bm,
                                              const float* __restrict__ aq,
                                              const float* __restrict__ am,
                                              const float* __restrict__ bres,
                                              unsigned short* __restrict__ out, int blk) {
  int row = blk * 4 + (threadIdx.x >> 6);
  if (row >= NN) return;
  int lane = threadIdx.x & 63;
  int c0 = lane, c1 = lane + 64;
  float s = svec[row];
  if (dscale) s *= dscale[row];
  float hq0 = fmaxf(fmaf(s, Wq[c0], bq[c0]), 0.f);
  float hq1 = fmaxf(fmaf(s, Wq[c1], bq[c1]), 0.f);
  float h0 = fmaxf(bf2f(g[(size_t)row * 128 + c0]) + bm[c0], 0.f);
  float h1 = fmaxf(bf2f(g[(size_t)row * 128 + c1]) + bm[c1], 0.f);
  float dq = wsum64(hq0 * aq[c0] + hq1 * aq[c1]);
  float dm = wsum64(h0 * am[c0] + h1 * am[c1]);
  float mx = fmaxf(dq, dm);
  float e0 = expf(dq - mx), e1 = expf(dm - mx);
  float w0 = e0 / (e0 + e1), w1 = 1.f - w0;
  float r0 = fmaxf(w0 * hq0 + w1 * h0 + bf2f(gr[(size_t)row * 128 + c0]) + bres[c0], 0.f);
  float r1 = fmaxf(w0 * hq1 + w1 * h1 + bf2f(gr[(size_t)row * 128 + c1]) + bres[c1], 0.f);
  out[(size_t)row * 128 + c0] = f2bf(r0);
  out[(size_t)row * 128 + c1] = f2bf(r1);
}

__global__ void fuse_add2_k(const unsigned short* gA, const unsigned short* grA,
                            const float* svA, const float* dsA, const float* WqA,
                            const float* bqA, const float* bmA, const float* aqA,
                            const float* amA, const float* brA, unsigned short* outA,
                            const unsigned short* gB, const unsigned short* grB,
                            const float* svB, const float* dsB, const float* WqB,
                            const float* bqB, const float* bmB, const float* aqB,
                            const float* amB, const float* brB, unsigned short* outB,
                            int nblk) {
  int b = blockIdx.x;
  if (b < nblk)
    fuse_add_body(gA, grA, svA, dsA, WqA, bqA, bmA, aqA, amA, brA, outA, b);
  else
    fuse_add_body(gB, grB, svB, dsB, WqB, bqB, bmB, aqB, amB, brB, outB, b - nblk);
}

// ---------- per-row cosine logits (bf16 z, q-norms computed locally) ----------
__global__ void sim_k(const unsigned short* __restrict__ z,
                      const unsigned short* __restrict__ za, const int* __restrict__ qp,
                      float4* __restrict__ simbuf, float* __restrict__ scal_out) {
  int row = blockIdx.x * 4 + (threadIdx.x >> 6);
  if (row >= NN) return;
  int lane = threadIdx.x & 63;
  int c0 = lane, c1 = lane + 64;
  int q = *qp;
  float zi0 = bf2f(z[(size_t)row * 128 + c0]), zi1 = bf2f(z[(size_t)row * 128 + c1]);
  float zai0 = bf2f(za[(size_t)row * 128 + c0]), zai1 = bf2f(za[(size_t)row * 128 + c1]);
  float zq0 = bf2f(z[(size_t)q * 128 + c0]), zq1 = bf2f(z[(size_t)q * 128 + c1]);
  float zaq0 = bf2f(za[(size_t)q * 128 + c0]), zaq1 = bf2f(za[(size_t)q * 128 + c1]);
  float nzi = wsum64(zi0 * zi0 + zi1 * zi1);
  float nzai = wsum64(zai0 * zai0 + zai1 * zai1);
  float nzq = wsum64(zq0 * zq0 + zq1 * zq1);
  float nzaq = wsum64(zaq0 * zaq0 + zaq1 * zaq1);
  float d1 = wsum64(zi0 * zq0 + zi1 * zq1);
  float d2 = wsum64(zai0 * zaq0 + zai1 * zaq1);
  float d3 = wsum64(zai0 * zq0 + zai1 * zq1);
  float d4 = wsum64(zi0 * zaq0 + zi1 * zaq1);
  if (lane == 0) {
    float ni = sqrtf(nzi), nai = sqrtf(nzai);
    float nq = sqrtf(nzq), naq = sqrtf(nzaq);
    float c1_ = d1 / fmaxf(ni * nq, 1e-8f) * TAU_INV;
    float ca1 = d2 / fmaxf(nai * naq, 1e-8f) * TAU_INV;
    float c2_ = d3 / fmaxf(nai * nq, 1e-8f) * TAU_INV;
    float ca2 = d4 / fmaxf(ni * naq, 1e-8f) * TAU_INV;
    simbuf[row] = make_float4(c1_, ca1, c2_, ca2);
    if (row == q) {
      scal_out[9] = c2_;
      scal_out[10] = ca2;
    }
  }
}

__global__ __launch_bounds__(256) void reduce_sim_k(const float4* __restrict__ simbuf,
                                                    const int* __restrict__ maskI,
                                                    float* __restrict__ scal) {
  float acc[9];
#pragma unroll
  for (int i = 0; i < 9; ++i) acc[i] = 0.f;
  for (int row = blockIdx.x * 256 + threadIdx.x; row < NN; row += gridDim.x * 256) {
    float4 v = simbuf[row];
    acc[0] += expf(v.x);
    acc[1] += expf(v.y);
    acc[2] += expf(v.z);
    acc[3] += expf(v.w);
    if (maskI[row]) {
      acc[4] += v.x; acc[5] += v.y; acc[6] += v.z; acc[7] += v.w;
      acc[8] += 1.0f;
    }
  }
  __shared__ float s[9][4];
  int lane = threadIdx.x & 63, wv = threadIdx.x >> 6;
#pragma unroll
  for (int i = 0; i < 9; ++i) {
    float r = wsum64(acc[i]);
    if (lane == 0) s[i][wv] = r;
  }
  __syncthreads();
  if (threadIdx.x < 9) {
    float r = s[threadIdx.x][0] + s[threadIdx.x][1] + s[threadIdx.x][2] + s[threadIdx.x][3];
    atomicAdd(&scal[threadIdx.x], r);
  }
}

__global__ void final_k(const float* __restrict__ scal, float* __restrict__ out) {
  if (threadIdx.x != 0 || blockIdx.x != 0) return;
  float S1 = scal[0], Sa1 = scal[1], S2 = scal[2], Sa2 = scal[3];
  float L1 = scal[4], La1 = scal[5], L2 = scal[6], La2 = scal[7];
  float NM = scal[8], Q2 = scal[9], Qa2 = scal[10];
  float intra = 0.5f * ((logf(S1) - L1 / NM) + (logf(Sa1) - La1 / NM));
  float inter = 0.5f * ((logf(S2) - L2 / NM) + (logf(Sa2) - La2 / NM));
  float unsup = 0.5f * (logf(S2) - Q2) + 0.5f * (logf(Sa2) - Qa2);
  out[0] = intra + 0.5f * inter + 0.5f * unsup;  // ALPHA=0.5, LAM=0.5
}

// ---------- host ----------
extern "C" void kernel_launch(void* const* d_in, const int* in_sizes, int n_in,
                              void* d_out, int out_size, void* d_ws, size_t ws_size,
                              hipStream_t stream) {
  const float* feats = (const float*)d_in[0];
  const int* ei = (const int*)d_in[1];
  const int* ea = (const int*)d_in[2];
  const int* pos = (const int*)d_in[3];
  const int* qp = (const int*)d_in[4];
  const float* Wq0 = (const float*)d_in[5];
  const float* bq0 = (const float*)d_in[6];
  const float* W0 = (const float*)d_in[7];
  const float* b0 = (const float*)d_in[8];
  const float* Whq0 = (const float*)d_in[9];
  const float* bhq0 = (const float*)d_in[10];
  const float* Wh0 = (const float*)d_in[11];
  const float* bh0 = (const float*)d_in[12];
  const float* Wf0 = (const float*)d_in[13];
  const float* bf0 = (const float*)d_in[14];
  const float* Wfh0 = (const float*)d_in[15];
  const float* bfh0 = (const float*)d_in[16];
  const float* aq0 = (const float*)d_in[17];
  const float* a0 = (const float*)d_in[18];
  const float* ahq0 = (const float*)d_in[19];
  const float* ah0 = (const float*)d_in[20];
  const float* aq_ = (const float*)d_in[21];
  const float* a_ = (const float*)d_in[22];
  const float* ahq_ = (const float*)d_in[23];
  const float* ah_ = (const float*)d_in[24];
  const float* Wlq = (const float*)d_in[25];
  const float* blq = (const float*)d_in[26];
  const float* Wlf = (const float*)d_in[27];
  const float* blf = (const float*)d_in[28];
  const float* Wm1 = (const float*)d_in[29];
  const float* bm1 = (const float*)d_in[30];
  const float* Wm2 = (const float*)d_in[31];
  const float* bm2 = (const float*)d_in[32];

  char* ws = (char*)d_ws;
  size_t off = 0;
  auto take = [&](size_t bytes) -> void* {
    void* p = ws + off;
    off = (off + bytes + 255) & ~(size_t)255;
    return p;
  };
  // ---- zero region ----
  int* cursor3 = (int*)take(3 * NN * 4);
  int* maskI = (int*)take(NN * 4);
  float* s_hq = (float*)take(NN * 4);
  float* cntq = (float*)take(NN * 4);
  float* s_hgq = (float*)take(NN * 4);
  float* scal = (float*)take(64 * 4);
  int* qcnt = (int*)take(24 * QPAD * 4);
  size_t zero_end = off;
  // ---- non-zeroed scratch ----
  unsigned short* slotsA = (unsigned short*)take((size_t)NN * CAP * 2);
  unsigned short* slotsB = (unsigned short*)take((size_t)NN * CAP * 2);
  unsigned short* slotsC = (unsigned short*)take((size_t)NN * CAP * 2);
  unsigned int* qdata = (unsigned int*)take((size_t)24 * QCAP * 4);
  float* dinv = (float*)take(NN * 4);
  float* Binv = (float*)take(NN * 4);
  float* Dninv = (float*)take(NN * 4);
  float4* simbuf = (float4*)take((size_t)NN * 16);
  unsigned short* Wpack = (unsigned short*)take((size_t)7 * 16384 * 2);
  const size_t BFSZ = (size_t)NN * HH * 2;
  unsigned short* B0 = (unsigned short*)take(BFSZ);
  unsigned short* B1 = (unsigned short*)take(BFSZ);
  unsigned short* B2 = (unsigned short*)take(BFSZ);
  unsigned short* B3 = (unsigned short*)take(BFSZ);
  unsigned short* B4 = (unsigned short*)take(BFSZ);
  unsigned short* B5 = (unsigned short*)take(BFSZ);
  unsigned short* B6 = (unsigned short*)take(BFSZ);  // feats2 bf16
  unsigned char* P1 = (unsigned char*)take((size_t)NN * 256);  // fp8 pair [node][2][128]
  unsigned char* P2 = (unsigned char*)take((size_t)NN * 256);
  unsigned char* P3 = (unsigned char*)take((size_t)NN * 256);

  const int EB = (EE + 255) / 256;
  const int GMB = (NN + 63) / 64;    // gemm blocks (64 rows each)
  const int GT4 = (NN + 3) / 4;      // gather blocks (4 nodes/block, 1 node/wave64)
  const int RB = (NN + 3) / 4;       // row-wave blocks
  const short8* Wp = (const short8*)Wpack;

  hipMemsetAsync(d_ws, 0, zero_end, stream);
  pack_k<<<(7 * 2048 + 255) / 256, 256, 0, stream>>>(W0, Wh0, Wlf, Wf0, Wfh0, Wm1, Wm2,
                                                     Wpack);
  // radix fill: bin edges once into (role x partition) queues, then LDS-cursor fill
  // (derive folded into fillp; maskI setup folded into bin block 0)
  bin_k<<<BINB, 256, 0, stream>>>(ei, ea, qcnt, qdata, pos, qp, maskI);
  fillp_k<<<24 * WSUB, 256, 0, stream>>>(qcnt, qdata, cursor3, slotsA, slotsB, slotsC,
                                         cntq, qp, dinv, Binv, Dninv);
  // feats @ {W0, Wh0, Wlf}: xw0 -> P1.half0 (fp8), xwh -> P2.half0 (fp8), feats2 -> B6 bf16
  gemm3_mfma<<<2 * GMB, 256, 0, stream>>>(feats, Wp, blf, P1, P2, B6, NN);
  // fused {shq | fuse2}: both ready after fillp+gemm3
  f2_k<<<EB + RB, 256, 0, stream>>>(ei, ea, qp, dinv, Binv, cntq, s_hq, s_hgq, B6, Wlq,
                                    blq, aq_, a_, ahq_, ah_, B3, B4, EB);
  // xwf -> P1.half1 ; xwfh -> P2.half1  (fp8, batched)
  gemm2_mfma<false, false, 2><<<2 * GMB, 256, 0, stream>>>(
      B3, B4, Wp + (size_t)3 * 2048, Wp + (size_t)4 * 2048, nullptr, nullptr, P1 + 128,
      P2 + 128, NN, GMB);
  // gathers: pass1 GCN P1 -> (B0=g0, B1=gf) bf16 ; pass2 HG-he P2 -> P3 fp8  [merged]
  dgather12_k<<<2 * GT4, 256, 0, stream>>>((const uint2*)P1, B0, B1, (const uint2*)P2,
                                           (uint2*)P3, cursor3, slotsA, slotsB, dinv, Binv,
                                           GT4);
  // pass3 HG-node P3 -> (B2, B5) bf16
  dgather3_k<<<GT4, 256, 0, stream>>>((const uint2*)P3, B2, B5, cursor3, slotsC, Dninv);
  // hf = B3 ; h_augf = B4  (batched fuse+residual+relu; B3/B4 free after gemm2 above)
  fuse_add2_k<<<2 * RB, 256, 0, stream>>>(
      B0, B1, s_hq, nullptr, Wq0, bq0, b0, aq0, a0, bf0, B3,
      B2, B5, s_hgq, Dninv, Whq0, bhq0, bh0, ahq0, ah0, bfh0, B4, RB);
  // MLPs (batched per layer): L1: (B3->B0),(B4->B1) ; L2: (B0->B2=z),(B1->B5=z_aug) bf16
  gemm2_mfma<true, true, 1><<<2 * GMB, 256, 0, stream>>>(
      B3, B4, Wp + (size_t)5 * 2048, Wp + (size_t)5 * 2048, bm1, bm1, B0, B1, NN, GMB);
  gemm2_mfma<true, false, 1><<<2 * GMB, 256, 0, stream>>>(
      B0, B1, Wp + (size_t)6 * 2048, Wp + (size_t)6 * 2048, bm2, bm2, B2, B5, NN, GMB);
  // loss
  sim_k<<<RB, 256, 0, stream>>>(B2, B5, qp, simbuf, scal);
  reduce_sim_k<<<64, 256, 0, stream>>>(simbuf, maskI, scal);
  final_k<<<1, 64, 0, stream>>>(scal, (float*)d_out);
}

// Round 10
// 420.985 us; speedup vs baseline: 1.0214x; 1.0214x over previous
//
#include <hip/hip_runtime.h>

#define NN 50000
#define EE 600000
#define HH 128
#define TAU_INV 2.0f   // 1/TAU, TAU=0.5
#define PSZ 6250       // NN / 8 partitions (partition <-> XCD fixed bijection)
#define CAP 48         // bucket capacity; max degree for multinomial(600k,1/50k) ~ 36

// radix-fill parameters
#define BINB 512                         // bin_k blocks
#define BUFC 240                         // per-(role,part) LDS buffer cap per BLOCK
#define QCAP 80000                       // per-(role,part) queue cap (mean 75000, +19 sigma)
#define QPAD 16                          // qcnt stride (ints) -> one counter per 64B line
#define WSUB 32                          // sub-ranges per (role,partition)
#define SUBN 196                         // ceil(PSZ/WSUB)

typedef __attribute__((ext_vector_type(8))) short short8;
typedef __attribute__((ext_vector_type(4))) float f32x4;
typedef __attribute__((ext_vector_type(2))) float floatx2;

// ---------- helpers ----------
__device__ __forceinline__ float wsum64(float v) {
#pragma unroll
  for (int m = 32; m >= 1; m >>= 1) v += __shfl_xor(v, m, 64);
  return v;
}
__device__ __forceinline__ unsigned short f2bf(float f) {
  unsigned u = __builtin_bit_cast(unsigned, f);
  u = u + 0x7FFFu + ((u >> 16) & 1u);
  return (unsigned short)(u >> 16);
}
__device__ __forceinline__ float bf2f(unsigned short h) {
  unsigned u = ((unsigned)h) << 16;
  return __builtin_bit_cast(float, u);
}
// fp8 e4m3 (OCP) via gfx950 HW converts
__device__ __forceinline__ unsigned char fp8_enc1(float v) {
  int p = __builtin_amdgcn_cvt_pk_fp8_f32(v, v, 0, false);
  return (unsigned char)(p & 0xFF);
}
__device__ __forceinline__ void fp8x8_dec(uint2 v, float* f) {
  floatx2 a = __builtin_amdgcn_cvt_pk_f32_fp8(v.x, false);
  floatx2 b = __builtin_amdgcn_cvt_pk_f32_fp8(v.x, true);
  floatx2 c = __builtin_amdgcn_cvt_pk_f32_fp8(v.y, false);
  floatx2 d = __builtin_amdgcn_cvt_pk_f32_fp8(v.y, true);
  f[0] = a.x; f[1] = a.y; f[2] = b.x; f[3] = b.y;
  f[4] = c.x; f[5] = c.y; f[6] = d.x; f[7] = d.y;
}
__device__ __forceinline__ uint2 fp8x8_enc(const float* f) {
  int w0 = __builtin_amdgcn_cvt_pk_fp8_f32(f[0], f[1], 0, false);
  w0 = __builtin_amdgcn_cvt_pk_fp8_f32(f[2], f[3], w0, true);
  int w1 = __builtin_amdgcn_cvt_pk_fp8_f32(f[4], f[5], 0, false);
  w1 = __builtin_amdgcn_cvt_pk_fp8_f32(f[6], f[7], w1, true);
  return make_uint2((unsigned)w0, (unsigned)w1);
}

#define LDSW 136  // 128 + 8 bf16 pad

// ---------- phase 1: bin edges into (role x partition) queues ----------
// Reads each edge ONCE; grid-stride accumulation into LDS with no intermediate
// barriers; ONE global alloc atomic per (block,group); flattened prefix copy-out.
// Block 0 also does maskI setup.
// role 0: key=dst, pay=src (GCN)   role 1: key=he, pay=node   role 2: key=node, pay=he
__global__ __launch_bounds__(256) void bin_k(const int* __restrict__ ei,
                                             const int* __restrict__ ea,
                                             int* __restrict__ qcnt,
                                             unsigned int* __restrict__ qdata,
                                             const int* __restrict__ pos,
                                             const int* __restrict__ qp,
                                             int* __restrict__ maskI) {
  __shared__ int cnt[24], base[24], pfx[25];
  __shared__ unsigned int buf[24 * BUFC];
  const int tid = threadIdx.x;
  if (tid < 24) cnt[tid] = 0;
  if (blockIdx.x == 0 && tid < 100) maskI[pos[tid]] = 1;
  __syncthreads();
  if (blockIdx.x == 0 && tid == 0) maskI[*qp] = 0;
  for (int e = blockIdx.x * 256 + tid; e < EE; e += BINB * 256) {
    int pay0 = __builtin_nontemporal_load(ei + e);      // src
    int k0 = __builtin_nontemporal_load(ei + EE + e);   // dst
    int pay1 = __builtin_nontemporal_load(ea + e);      // node
    int k1 = __builtin_nontemporal_load(ea + EE + e);   // he
    int k2 = pay1, pay2 = k1;
    int g0 = k0 / PSZ;
    int g1 = 8 + k1 / PSZ;
    int g2 = 16 + k2 / PSZ;
    int o0 = atomicAdd(&cnt[g0], 1);
    int o1 = atomicAdd(&cnt[g1], 1);
    int o2 = atomicAdd(&cnt[g2], 1);
    if (o0 < BUFC) buf[g0 * BUFC + o0] = ((unsigned)k0 << 16) | (unsigned)pay0;
    if (o1 < BUFC) buf[g1 * BUFC + o1] = ((unsigned)k1 << 16) | (unsigned)pay1;
    if (o2 < BUFC) buf[g2 * BUFC + o2] = ((unsigned)k2 << 16) | (unsigned)pay2;
  }
  __syncthreads();
  if (tid < 24) {
    int c = min(cnt[tid], BUFC);
    cnt[tid] = c;
    base[tid] = atomicAdd(&qcnt[tid * QPAD], c);  // padded: 1 counter per 64B line
  }
  __syncthreads();
  if (tid == 0) {
    int s = 0;
#pragma unroll
    for (int g = 0; g < 24; ++g) { pfx[g] = s; s += cnt[g]; }
    pfx[24] = s;
  }
  __syncthreads();
  const int total = pfx[24];
  for (int j = tid; j < total; j += 256) {
    int lo2 = 0, hi2 = 24;
    while (lo2 + 1 < hi2) {
      int mid = (lo2 + hi2) >> 1;
      if (j >= pfx[mid]) lo2 = mid; else hi2 = mid;
    }
    int g = lo2;
    int i = j - pfx[g];
    int dq = base[g] + i;
    if (dq < QCAP) qdata[(size_t)g * QCAP + dq] = buf[g * BUFC + i];
  }
}

// ---------- phase 2: partitioned fill with LDS cursors (+ fused derive) ----------
__global__ __launch_bounds__(256) void fillp_k(const int* __restrict__ qcnt,
                                               const unsigned int* __restrict__ qdata,
                                               int* __restrict__ cursor,
                                               unsigned short* __restrict__ slotsA,
                                               unsigned short* __restrict__ slotsB,
                                               unsigned short* __restrict__ slotsC,
                                               float* __restrict__ cntq,
                                               const int* __restrict__ qp,
                                               float* __restrict__ dinv,
                                               float* __restrict__ Binv,
                                               float* __restrict__ Dninv) {
  __shared__ int cur[SUBN];
  const int w = blockIdx.x;  // 0..767
  const int p = w & 7;
  const int r = (w >> 3) % 3;
  const int s = w / 24;
  const int lo = p * PSZ + s * SUBN;
  const int hi = min(lo + SUBN, (p + 1) * PSZ);
  const int tid = threadIdx.x;
  if (tid < SUBN) cur[tid] = 0;
  __syncthreads();
  const int g = r * 8 + p;
  const int qlen = min(qcnt[g * QPAD], QCAP);
  const unsigned int* qd = qdata + (size_t)g * QCAP;
  unsigned short* slots = (r == 0) ? slotsA : (r == 1) ? slotsB : slotsC;
  const int q = *qp;
  auto proc = [&](unsigned int rec) {
    int key = (int)(rec >> 16);
    if (key >= lo && key < hi) {
      int pay = (int)(rec & 0xFFFFu);
      int idx = atomicAdd(&cur[key - lo], 1);
      if (idx < CAP) slots[key * CAP + idx] = (unsigned short)pay;
      if (r == 1 && pay == q) atomicAdd(&cntq[key], 1.0f);
    }
  };
  const int nv4 = qlen >> 2;
  const uint4* qd4 = (const uint4*)qd;
  int j = tid;
  for (; j + 256 < nv4; j += 512) {
    uint4 r0 = qd4[j];
    uint4 r1 = qd4[j + 256];
    proc(r0.x); proc(r0.y); proc(r0.z); proc(r0.w);
    proc(r1.x); proc(r1.y); proc(r1.z); proc(r1.w);
  }
  if (j < nv4) {
    uint4 r0 = qd4[j];
    proc(r0.x); proc(r0.y); proc(r0.z); proc(r0.w);
  }
  int i = (nv4 << 2) + tid;
  if (i < qlen) proc(qd[i]);
  __syncthreads();
  for (int k = lo + tid; k < hi; k += 256) {
    int c = cur[k - lo];
    cursor[r * NN + k] = c;
    if (r == 0) dinv[k] = rsqrtf((float)(c + 1));            // deg incl. self-loop
    else if (r == 1) Binv[k] = (c > 0) ? 1.0f / (float)c : 0.0f;
    else Dninv[k] = (c > 0) ? 1.0f / (float)c : 0.0f;
  }
}

// ---------- shq body: analytic query coefficients ----------
__device__ __forceinline__ void shq_body(const int* __restrict__ ei, const int* __restrict__ ea,
                                         const int* __restrict__ qp,
                                         const float* __restrict__ dinv,
                                         const float* __restrict__ Binv,
                                         const float* __restrict__ cntq,
                                         float* __restrict__ s_hq, float* __restrict__ s_hgq,
                                         int bid) {
  int e = bid * 256 + threadIdx.x;
  if (e >= EE) return;
  int q = *qp;
  int src = __builtin_nontemporal_load(ei + e);
  if (src == q) {
    int dst = __builtin_nontemporal_load(ei + EE + e);
    atomicAdd(&s_hq[dst], dinv[q] * dinv[dst]);
  }
  int he = __builtin_nontemporal_load(ea + EE + e);
  float cq = cntq[he];
  if (cq != 0.0f) {
    int node = __builtin_nontemporal_load(ea + e);
    atomicAdd(&s_hgq[node], Binv[he] * cq);
  }
  if (e == 0) atomicAdd(&s_hq[q], dinv[q] * dinv[q]);  // self-loop of query gcn
}

// ---------- fuse2 body: hf_ and hfh_ from analytic querys2 and feats2(bf16) ----------
__device__ __forceinline__ void fuse2_body(const unsigned short* __restrict__ f2,
                                           const int* __restrict__ qp,
                                           const float* __restrict__ Wlq,
                                           const float* __restrict__ blq,
                                           const float* __restrict__ aq1,
                                           const float* __restrict__ a1,
                                           const float* __restrict__ aq2,
                                           const float* __restrict__ a2,
                                           unsigned short* __restrict__ out1,
                                           unsigned short* __restrict__ out2, int bid) {
  int row = bid * 4 + (threadIdx.x >> 6);
  if (row >= NN) return;
  int lane = threadIdx.x & 63;
  int c0 = lane, c1 = lane + 64;
  int q = *qp;
  float q20 = blq[c0] + ((row == q) ? Wlq[c0] : 0.f);
  float q21 = blq[c1] + ((row == q) ? Wlq[c1] : 0.f);
  float f0 = bf2f(f2[(size_t)row * 128 + c0]);
  float f1 = bf2f(f2[(size_t)row * 128 + c1]);
  float dq1 = wsum64(q20 * aq1[c0] + q21 * aq1[c1]);
  float df1 = wsum64(f0 * a1[c0] + f1 * a1[c1]);
  float dq2 = wsum64(q20 * aq2[c0] + q21 * aq2[c1]);
  float df2 = wsum64(f0 * a2[c0] + f1 * a2[c1]);
  {
    float mx = fmaxf(dq1, df1);
    float e0 = expf(dq1 - mx), e1 = expf(df1 - mx);
    float w0 = e0 / (e0 + e1), w1 = 1.f - w0;
    out1[(size_t)row * 128 + c0] = f2bf(w0 * q20 + w1 * f0);
    out1[(size_t)row * 128 + c1] = f2bf(w0 * q21 + w1 * f1);
  }
  {
    float mx = fmaxf(dq2, df2);
    float e0 = expf(dq2 - mx), e1 = expf(df2 - mx);
    float w0 = e0 / (e0 + e1), w1 = 1.f - w0;
    out2[(size_t)row * 128 + c0] = f2bf(w0 * q20 + w1 * f0);
    out2[(size_t)row * 128 + c1] = f2bf(w0 * q21 + w1 * f1);
  }
}

// ---------- fused f2: {shq | fuse2} ----------
__global__ __launch_bounds__(256) void f2_k(const int* __restrict__ ei,
                                            const int* __restrict__ ea,
                                            const int* __restrict__ qp,
                                            const float* __restrict__ dinv,
                                            const float* __restrict__ Binv,
                                            const float* __restrict__ cntq,
                                            float* __restrict__ s_hq,
                                            float* __restrict__ s_hgq,
                                            const unsigned short* __restrict__ B6,
                                            const float* __restrict__ Wlq,
                                            const float* __restrict__ blq,
                                            const float* __restrict__ aq_,
                                            const float* __restrict__ a_,
                                            const float* __restrict__ ahq_,
                                            const float* __restrict__ ah_,
                                            unsigned short* __restrict__ B3,
                                            unsigned short* __restrict__ B4, int eb) {
  int b = blockIdx.x;
  if (b < eb)
    shq_body(ei, ea, qp, dinv, Binv, cntq, s_hq, s_hgq, b);
  else
    fuse2_body(B6, qp, Wlq, blq, aq_, a_, ahq_, ah_, B3, B4, b - eb);
}

// ---------- pack 7 weight matrices into MFMA B-fragment order ----------
__global__ void pack_k(const float* __restrict__ W0, const float* __restrict__ Wh0,
                       const float* __restrict__ Wlf, const float* __restrict__ Wf0,
                       const float* __restrict__ Wfh0, const float* __restrict__ Wm1,
                       const float* __restrict__ Wm2, unsigned short* __restrict__ out) {
  int tid = blockIdx.x * 256 + threadIdx.x;
  if (tid >= 7 * 2048) return;
  int mat = tid >> 11, r = tid & 2047;
  int s = r >> 9, c = (r >> 6) & 7, lane = r & 63;
  const float* W = (mat == 0) ? W0 : (mat == 1) ? Wh0 : (mat == 2) ? Wlf
                 : (mat == 3) ? Wf0 : (mat == 4) ? Wfh0 : (mat == 5) ? Wm1 : Wm2;
  int k0 = 32 * s + (lane >> 4) * 8;
  int n = 16 * c + (lane & 15);
  unsigned short* o = out + (size_t)tid * 8;
#pragma unroll
  for (int j = 0; j < 8; ++j) o[j] = f2bf(W[(k0 + j) * 128 + n]);
}

// ---------- gemm core (A staged in LDS as bf16; LDS-staged coalesced epilogue) ----------
// OM: 1 = bf16 out (ushort stride 128), 2 = fp8 out (uchar stride 256).
template <bool BIAS, bool RELU, int OM>
__device__ __forceinline__ void gemm_core(unsigned short* As, const short8* Wp,
                                          const float* bias, void* outv, int r0, int nrows,
                                          int tid) {
  const int wave = tid >> 6, lane = tid & 63;
  const int quad = lane >> 4, l15 = lane & 15;
  f32x4 acc[8];
#pragma unroll
  for (int c = 0; c < 8; ++c) acc[c] = (f32x4){0.f, 0.f, 0.f, 0.f};
#pragma unroll
  for (int s = 0; s < 4; ++s) {
    short8 a = *(const short8*)&As[(wave * 16 + l15) * LDSW + s * 32 + quad * 8];
#pragma unroll
    for (int c = 0; c < 8; ++c) {
      short8 b = Wp[(s * 8 + c) * 64 + lane];
      acc[c] = __builtin_amdgcn_mfma_f32_16x16x32_bf16(a, b, acc[c], 0, 0, 0);
    }
  }
  __syncthreads();  // all waves done reading As before overwrite
  const int rwl = wave * 16 + quad * 4;  // local row base
  if (OM == 2) {
    unsigned char* l8 = (unsigned char*)As;  // [64][128] fp8 = 8KB
#pragma unroll
    for (int c = 0; c < 8; ++c) {
      int col = c * 16 + l15;
      float bv = BIAS ? bias[col] : 0.f;
#pragma unroll
      for (int r = 0; r < 4; ++r) {
        float v = acc[c][r] + bv;
        if (RELU) v = fmaxf(v, 0.f);
        l8[(rwl + r) * 128 + col] = fp8_enc1(v);
      }
    }
    __syncthreads();
#pragma unroll
    for (int t = 0; t < 2; ++t) {
      int idx = (t * 256 + tid) * 16;  // 0..8191
      int row = idx >> 7, off = idx & 127;
      int grow = r0 + row;
      if (grow < nrows)
        *(uint4*)&((unsigned char*)outv)[(size_t)grow * 256 + off] = *(uint4*)&l8[idx];
    }
  } else {
    unsigned short* l16 = As;  // [64][128] ushort = 16KB
#pragma unroll
    for (int c = 0; c < 8; ++c) {
      int col = c * 16 + l15;
      float bv = BIAS ? bias[col] : 0.f;
#pragma unroll
      for (int r = 0; r < 4; ++r) {
        float v = acc[c][r] + bv;
        if (RELU) v = fmaxf(v, 0.f);
        l16[(rwl + r) * 128 + col] = f2bf(v);
      }
    }
    __syncthreads();
#pragma unroll
    for (int t = 0; t < 4; ++t) {
      int idx = (t * 256 + tid) * 16;  // byte idx 0..16383
      int row = idx >> 8, off = idx & 255;
      int grow = r0 + row;
      if (grow < nrows)
        *(uint4*)&((unsigned char*)outv)[(size_t)grow * 256 + off] =
            *(uint4*)&((unsigned char*)l16)[idx];
    }
  }
}

__device__ __forceinline__ void stage_bf16(const unsigned short* A, unsigned short* As,
                                           int r0, int nrows, int tid) {
#pragma unroll
  for (int t = 0; t < 4; ++t) {
    int v = t * 256 + tid;
    int row = v >> 4, cc = v & 15;
    int gr = r0 + row;
    uint4 val = make_uint4(0, 0, 0, 0);
    if (gr < nrows) val = ((const uint4*)A)[(size_t)gr * 16 + cc];
    *(uint4*)&As[row * LDSW + cc * 8] = val;
  }
}

// ---------- batched pair GEMM: two independent A@W ----------
template <bool BIAS, bool RELU, int OM>
__global__ __launch_bounds__(256) void gemm2_mfma(const unsigned short* __restrict__ A0,
                                                  const unsigned short* __restrict__ A1,
                                                  const short8* __restrict__ Wp0,
                                                  const short8* __restrict__ Wp1,
                                                  const float* __restrict__ b0,
                                                  const float* __restrict__ b1,
                                                  void* __restrict__ o0, void* __restrict__ o1,
                                                  int nrows, int nblk) {
  __shared__ unsigned short As[64 * LDSW];
  int b = blockIdx.x;
  const unsigned short* A = A0;
  const short8* Wp = Wp0;
  const float* bias = b0;
  void* o = o0;
  if (b >= nblk) {
    b -= nblk; A = A1; Wp = Wp1; bias = b1; o = o1;
  }
  const int r0 = b * 64;
  stage_bf16(A, As, r0, nrows, threadIdx.x);
  __syncthreads();
  gemm_core<BIAS, RELU, OM>(As, Wp, bias, o, r0, nrows, threadIdx.x);
}

// ---------- 3 GEMMs sharing one fp32-A tile; column-halved for occupancy ----------
__global__ __launch_bounds__(256) void gemm3_mfma(const float* __restrict__ A,
                                                  const short8* __restrict__ Wp,  // mats 0,1,2
                                                  const float* __restrict__ bias2,
                                                  unsigned char* __restrict__ p1,
                                                  unsigned char* __restrict__ p2,
                                                  unsigned short* __restrict__ out2,
                                                  int nrows) {
  __shared__ unsigned short As[64 * LDSW];
  const int tid = threadIdx.x;
  const int bh = blockIdx.x & 1;
  const int r0 = (blockIdx.x >> 1) * 64;
#pragma unroll
  for (int t = 0; t < 8; ++t) {
    int v = t * 256 + tid;
    int row = v >> 5, c4 = v & 31;  // float4 chunk
    int gr = r0 + row;
    f32x4 val = (f32x4){0.f, 0.f, 0.f, 0.f};
    if (gr < nrows) val = ((const f32x4*)A)[(size_t)gr * 32 + c4];  // plain: L3 reuse
    ushort4 o;
    o.x = f2bf(val.x); o.y = f2bf(val.y); o.z = f2bf(val.z); o.w = f2bf(val.w);
    *(ushort4*)&As[row * LDSW + c4 * 4] = o;
  }
  __syncthreads();
  const int wave = tid >> 6, lane = tid & 63;
  const int quad = lane >> 4, l15 = lane & 15;
  f32x4 acc[3][4];
#pragma unroll
  for (int m = 0; m < 3; ++m)
#pragma unroll
    for (int c = 0; c < 4; ++c) acc[m][c] = (f32x4){0.f, 0.f, 0.f, 0.f};
#pragma unroll
  for (int s = 0; s < 4; ++s) {
    short8 a = *(const short8*)&As[(wave * 16 + l15) * LDSW + s * 32 + quad * 8];
#pragma unroll
    for (int m = 0; m < 3; ++m)
#pragma unroll
      for (int c = 0; c < 4; ++c) {
        short8 bb = Wp[(size_t)m * 2048 + (s * 8 + bh * 4 + c) * 64 + lane];
        acc[m][c] = __builtin_amdgcn_mfma_f32_16x16x32_bf16(a, bb, acc[m][c], 0, 0, 0);
      }
  }
  __syncthreads();  // done reading As
  // stage outputs: P1 [64][64]B @0, P2 @4096, B6 [64][64]ushort @8192 (16KB total)
  unsigned char* l8a = (unsigned char*)As;
  unsigned char* l8b = l8a + 4096;
  unsigned short* l16 = (unsigned short*)(l8a + 8192);
  const int rwl = wave * 16 + quad * 4;
#pragma unroll
  for (int c = 0; c < 4; ++c) {
    int coll = c * 16 + l15;                 // local col 0..63
    float bv = bias2[(bh * 4 + c) * 16 + l15];
#pragma unroll
    for (int r = 0; r < 4; ++r) {
      int lrow = rwl + r;
      l8a[lrow * 64 + coll] = fp8_enc1(acc[0][c][r]);
      l8b[lrow * 64 + coll] = fp8_enc1(acc[1][c][r]);
      l16[lrow * 64 + coll] = f2bf(acc[2][c][r] + bv);
    }
  }
  __syncthreads();
  {  // P1/P2: 4KB each, 16B per thread, rows are 64B-contiguous chunks
    int idx = tid * 16;
    int row = idx >> 6, off = idx & 63;
    int grow = r0 + row;
    if (grow < nrows) {
      *(uint4*)&p1[(size_t)grow * 256 + bh * 64 + off] = *(uint4*)&l8a[idx];
      *(uint4*)&p2[(size_t)grow * 256 + bh * 64 + off] = *(uint4*)&l8b[idx];
    }
  }
#pragma unroll
  for (int t = 0; t < 2; ++t) {  // B6: 8KB, rows are 128B-contiguous chunks
    int idx = (t * 256 + tid) * 16;
    int row = idx >> 7, off = idx & 127;
    int grow = r0 + row;
    if (grow < nrows)
      *(uint4*)&((unsigned char*)out2)[(size_t)grow * 256 + bh * 128 + off] =
          *(uint4*)&((unsigned char*)l16)[idx];
  }
}

// ---------- paired gather (bucket CSR), fp8-pair input, 4x-unrolled (R8 formulation:
// 8 nodes/block, 32 lanes/node — measured best; R9's wave-per-node variant regressed) ----
// MODE 0: y[i] = wv[i]*(wv[i]*x[i] + sum_s wv[s]*x[s])   (GCN w/ self-loop)
// MODE 1: y[i] = wv[i]*sum_s x[s]                         (hypergraph halves)
template <int MODE, bool OUTFP8>
__device__ __forceinline__ void gpair_body(const uint2* __restrict__ xp,
                                           unsigned short* __restrict__ y1,
                                           unsigned short* __restrict__ y2,
                                           uint2* __restrict__ yp,
                                           const int* __restrict__ cnt,
                                           const unsigned short* __restrict__ slots,
                                           const float* __restrict__ wv, int blk) {
  int node = blk * 8 + (threadIdx.x >> 5);
  if (node >= NN) return;
  int l = threadIdx.x & 31;
  int st = node * CAP;
  int n = min(cnt[node], CAP);
  float acc[8];
#pragma unroll
  for (int i = 0; i < 8; ++i) acc[i] = 0.f;
  int p = 0;
  for (; p + 4 <= n; p += 4) {
    ushort4 s4 = *(const ushort4*)&slots[st + p];
    uint2 v0 = xp[(size_t)s4.x * 32 + l];
    uint2 v1 = xp[(size_t)s4.y * 32 + l];
    uint2 v2 = xp[(size_t)s4.z * 32 + l];
    uint2 v3 = xp[(size_t)s4.w * 32 + l];
    float f[8];
    if (MODE == 0) {
      float w0 = wv[s4.x], w1 = wv[s4.y], w2 = wv[s4.z], w3 = wv[s4.w];
      fp8x8_dec(v0, f);
#pragma unroll
      for (int i = 0; i < 8; ++i) acc[i] = fmaf(w0, f[i], acc[i]);
      fp8x8_dec(v1, f);
#pragma unroll
      for (int i = 0; i < 8; ++i) acc[i] = fmaf(w1, f[i], acc[i]);
      fp8x8_dec(v2, f);
#pragma unroll
      for (int i = 0; i < 8; ++i) acc[i] = fmaf(w2, f[i], acc[i]);
      fp8x8_dec(v3, f);
#pragma unroll
      for (int i = 0; i < 8; ++i) acc[i] = fmaf(w3, f[i], acc[i]);
    } else {
      fp8x8_dec(v0, f);
#pragma unroll
      for (int i = 0; i < 8; ++i) acc[i] += f[i];
      fp8x8_dec(v1, f);
#pragma unroll
      for (int i = 0; i < 8; ++i) acc[i] += f[i];
      fp8x8_dec(v2, f);
#pragma unroll
      for (int i = 0; i < 8; ++i) acc[i] += f[i];
      fp8x8_dec(v3, f);
#pragma unroll
      for (int i = 0; i < 8; ++i) acc[i] += f[i];
    }
  }
  for (; p < n; ++p) {
    int s = slots[st + p];
    uint2 v = xp[(size_t)s * 32 + l];
    float f[8];
    fp8x8_dec(v, f);
    if (MODE == 0) {
      float w = wv[s];
#pragma unroll
      for (int i = 0; i < 8; ++i) acc[i] = fmaf(w, f[i], acc[i]);
    } else {
#pragma unroll
      for (int i = 0; i < 8; ++i) acc[i] += f[i];
    }
  }
  float sc = wv[node];
  if (MODE == 0) {
    uint2 v = xp[(size_t)node * 32 + l];
    float f[8];
    fp8x8_dec(v, f);
#pragma unroll
    for (int i = 0; i < 8; ++i) acc[i] = sc * fmaf(sc, f[i], acc[i]);
  } else {
#pragma unroll
    for (int i = 0; i < 8; ++i) acc[i] *= sc;
  }
  if (OUTFP8) {
    yp[(size_t)node * 32 + l] = fp8x8_enc(acc);
  } else {
    unsigned short* y = (l < 16) ? y1 : y2;
    int cg = l & 15;
    uint4 o;
    o.x = ((unsigned)f2bf(acc[1]) << 16) | f2bf(acc[0]);
    o.y = ((unsigned)f2bf(acc[3]) << 16) | f2bf(acc[2]);
    o.z = ((unsigned)f2bf(acc[5]) << 16) | f2bf(acc[4]);
    o.w = ((unsigned)f2bf(acc[7]) << 16) | f2bf(acc[6]);
    *(uint4*)&y[(size_t)node * 128 + cg * 8] = o;
  }
}

// merged: pass1 (GCN, MODE0, slotsA, bf16 outs) + pass2 (HG-he, MODE1, slotsB, fp8-pair out)
__global__ void dgather12_k(const uint2* __restrict__ xp1, unsigned short* __restrict__ y1a,
                            unsigned short* __restrict__ y1b, const uint2* __restrict__ xp2,
                            uint2* __restrict__ yp3, const int* __restrict__ cursor,
                            const unsigned short* __restrict__ slotsA,
                            const unsigned short* __restrict__ slotsB,
                            const float* __restrict__ dinv, const float* __restrict__ Binv,
                            int nblk) {
  int b = blockIdx.x;
  if (b < nblk)
    gpair_body<0, false>(xp1, y1a, y1b, nullptr, cursor, slotsA, dinv, b);
  else
    gpair_body<1, true>(xp2, nullptr, nullptr, yp3, cursor + NN, slotsB, Binv, b - nblk);
}

__global__ void dgather3_k(const uint2* __restrict__ xp, unsigned short* __restrict__ y1,
                           unsigned short* __restrict__ y2, const int* __restrict__ cursor,
                           const unsigned short* __restrict__ slotsC,
                           const float* __restrict__ wv) {
  gpair_body<1, false>(xp, y1, y2, nullptr, cursor + 2 * NN, slotsC, wv, blockIdx.x);
}

// ---------- fused: fuse(analytic-query, conv) + residual + relu -> bf16 (batched x2) -----
__device__ __forceinline__ void fuse_add_body(const unsigned short* __restrict__ g,
                                              const unsigned short* __restrict__ gr,
                                              const float* __restrict__ svec,
                                              const float* __restrict__ dscale,
                                              const float* __restrict__ Wq,
                                              const float* __restrict__ bq,
                                              const float* __restrict__ bm,
                                              const float* __restrict__ aq,
                                              const float* __restrict__ am,
                                              const float* __restrict__ bres,
                                              unsigned short* __restrict__ out, int blk) {
  int row = blk * 4 + (threadIdx.x >> 6);
  if (row >= NN) return;
  int lane = threadIdx.x & 63;
  int c0 = lane, c1 = lane + 64;
  float s = svec[row];
  if (dscale) s *= dscale[row];
  float hq0 = fmaxf(fmaf(s, Wq[c0], bq[c0]), 0.f);
  float hq1 = fmaxf(fmaf(s, Wq[c1], bq[c1]), 0.f);
  float h0 = fmaxf(bf2f(g[(size_t)row * 128 + c0]) + bm[c0], 0.f);
  float h1 = fmaxf(bf2f(g[(size_t)row * 128 + c1]) + bm[c1], 0.f);
  float dq = wsum64(hq0 * aq[c0] + hq1 * aq[c1]);
  float dm = wsum64(h0 * am[c0] + h1 * am[c1]);
  float mx = fmaxf(dq, dm);
  float e0 = expf(dq - mx), e1 = expf(dm - mx);
  float w0 = e0 / (e0 + e1), w1 = 1.f - w0;
  float r0 = fmaxf(w0 * hq0 + w1 * h0 + bf2f(gr[(size_t)row * 128 + c0]) + bres[c0], 0.f);
  float r1 = fmaxf(w0 * hq1 + w1 * h1 + bf2f(gr[(size_t)row * 128 + c1]) + bres[c1], 0.f);
  out[(size_t)row * 128 + c0] = f2bf(r0);
  out[(size_t)row * 128 + c1] = f2bf(r1);
}

__global__ void fuse_add2_k(const unsigned short* gA, const unsigned short* grA,
                            const float* svA, const float* dsA, const float* WqA,
                            const float* bqA, const float* bmA, const float* aqA,
                            const float* amA, const float* brA, unsigned short* outA,
                            const unsigned short* gB, const unsigned short* grB,
                            const float* svB, const float* dsB, const float* WqB,
                            const float* bqB, const float* bmB, const float* aqB,
                            const float* amB, const float* brB, unsigned short* outB,
                            int nblk) {
  int b = blockIdx.x;
  if (b < nblk)
    fuse_add_body(gA, grA, svA, dsA, WqA, bqA, bmA, aqA, amA, brA, outA, b);
  else
    fuse_add_body(gB, grB, svB, dsB, WqB, bqB, bmB, aqB, amB, brB, outB, b - nblk);
}

// ---------- per-row cosine logits (bf16 z, q-norms computed locally) ----------
__global__ void sim_k(const unsigned short* __restrict__ z,
                      const unsigned short* __restrict__ za, const int* __restrict__ qp,
                      float4* __restrict__ simbuf, float* __restrict__ scal_out) {
  int row = blockIdx.x * 4 + (threadIdx.x >> 6);
  if (row >= NN) return;
  int lane = threadIdx.x & 63;
  int c0 = lane, c1 = lane + 64;
  int q = *qp;
  float zi0 = bf2f(z[(size_t)row * 128 + c0]), zi1 = bf2f(z[(size_t)row * 128 + c1]);
  float zai0 = bf2f(za[(size_t)row * 128 + c0]), zai1 = bf2f(za[(size_t)row * 128 + c1]);
  float zq0 = bf2f(z[(size_t)q * 128 + c0]), zq1 = bf2f(z[(size_t)q * 128 + c1]);
  float zaq0 = bf2f(za[(size_t)q * 128 + c0]), zaq1 = bf2f(za[(size_t)q * 128 + c1]);
  float nzi = wsum64(zi0 * zi0 + zi1 * zi1);
  float nzai = wsum64(zai0 * zai0 + zai1 * zai1);
  float nzq = wsum64(zq0 * zq0 + zq1 * zq1);
  float nzaq = wsum64(zaq0 * zaq0 + zaq1 * zaq1);
  float d1 = wsum64(zi0 * zq0 + zi1 * zq1);
  float d2 = wsum64(zai0 * zaq0 + zai1 * zaq1);
  float d3 = wsum64(zai0 * zq0 + zai1 * zq1);
  float d4 = wsum64(zi0 * zaq0 + zi1 * zaq1);
  if (lane == 0) {
    float ni = sqrtf(nzi), nai = sqrtf(nzai);
    float nq = sqrtf(nzq), naq = sqrtf(nzaq);
    float c1_ = d1 / fmaxf(ni * nq, 1e-8f) * TAU_INV;
    float ca1 = d2 / fmaxf(nai * naq, 1e-8f) * TAU_INV;
    float c2_ = d3 / fmaxf(nai * nq, 1e-8f) * TAU_INV;
    float ca2 = d4 / fmaxf(ni * naq, 1e-8f) * TAU_INV;
    simbuf[row] = make_float4(c1_, ca1, c2_, ca2);
    if (row == q) {
      scal_out[9] = c2_;
      scal_out[10] = ca2;
    }
  }
}

__global__ __launch_bounds__(256) void reduce_sim_k(const float4* __restrict__ simbuf,
                                                    const int* __restrict__ maskI,
                                                    float* __restrict__ scal) {
  float acc[9];
#pragma unroll
  for (int i = 0; i < 9; ++i) acc[i] = 0.f;
  for (int row = blockIdx.x * 256 + threadIdx.x; row < NN; row += gridDim.x * 256) {
    float4 v = simbuf[row];
    acc[0] += expf(v.x);
    acc[1] += expf(v.y);
    acc[2] += expf(v.z);
    acc[3] += expf(v.w);
    if (maskI[row]) {
      acc[4] += v.x; acc[5] += v.y; acc[6] += v.z; acc[7] += v.w;
      acc[8] += 1.0f;
    }
  }
  __shared__ float s[9][4];
  int lane = threadIdx.x & 63, wv = threadIdx.x >> 6;
#pragma unroll
  for (int i = 0; i < 9; ++i) {
    float r = wsum64(acc[i]);
    if (lane == 0) s[i][wv] = r;
  }
  __syncthreads();
  if (threadIdx.x < 9) {
    float r = s[threadIdx.x][0] + s[threadIdx.x][1] + s[threadIdx.x][2] + s[threadIdx.x][3];
    atomicAdd(&scal[threadIdx.x], r);
  }
}

__global__ void final_k(const float* __restrict__ scal, float* __restrict__ out) {
  if (threadIdx.x != 0 || blockIdx.x != 0) return;
  float S1 = scal[0], Sa1 = scal[1], S2 = scal[2], Sa2 = scal[3];
  float L1 = scal[4], La1 = scal[5], L2 = scal[6], La2 = scal[7];
  float NM = scal[8], Q2 = scal[9], Qa2 = scal[10];
  float intra = 0.5f * ((logf(S1) - L1 / NM) + (logf(Sa1) - La1 / NM));
  float inter = 0.5f * ((logf(S2) - L2 / NM) + (logf(Sa2) - La2 / NM));
  float unsup = 0.5f * (logf(S2) - Q2) + 0.5f * (logf(Sa2) - Qa2);
  out[0] = intra + 0.5f * inter + 0.5f * unsup;  // ALPHA=0.5, LAM=0.5
}

// ---------- host ----------
extern "C" void kernel_launch(void* const* d_in, const int* in_sizes, int n_in,
                              void* d_out, int out_size, void* d_ws, size_t ws_size,
                              hipStream_t stream) {
  const float* feats = (const float*)d_in[0];
  const int* ei = (const int*)d_in[1];
  const int* ea = (const int*)d_in[2];
  const int* pos = (const int*)d_in[3];
  const int* qp = (const int*)d_in[4];
  const float* Wq0 = (const float*)d_in[5];
  const float* bq0 = (const float*)d_in[6];
  const float* W0 = (const float*)d_in[7];
  const float* b0 = (const float*)d_in[8];
  const float* Whq0 = (const float*)d_in[9];
  const float* bhq0 = (const float*)d_in[10];
  const float* Wh0 = (const float*)d_in[11];
  const float* bh0 = (const float*)d_in[12];
  const float* Wf0 = (const float*)d_in[13];
  const float* bf0 = (const float*)d_in[14];
  const float* Wfh0 = (const float*)d_in[15];
  const float* bfh0 = (const float*)d_in[16];
  const float* aq0 = (const float*)d_in[17];
  const float* a0 = (const float*)d_in[18];
  const float* ahq0 = (const float*)d_in[19];
  const float* ah0 = (const float*)d_in[20];
  const float* aq_ = (const float*)d_in[21];
  const float* a_ = (const float*)d_in[22];
  const float* ahq_ = (const float*)d_in[23];
  const float* ah_ = (const float*)d_in[24];
  const float* Wlq = (const float*)d_in[25];
  const float* blq = (const float*)d_in[26];
  const float* Wlf = (const float*)d_in[27];
  const float* blf = (const float*)d_in[28];
  const float* Wm1 = (const float*)d_in[29];
  const float* bm1 = (const float*)d_in[30];
  const float* Wm2 = (const float*)d_in[31];
  const float* bm2 = (const float*)d_in[32];

  char* ws = (char*)d_ws;
  size_t off = 0;
  auto take = [&](size_t bytes) -> void* {
    void* p = ws + off;
    off = (off + bytes + 255) & ~(size_t)255;
    return p;
  };
  // ---- zero region ----
  int* cursor3 = (int*)take(3 * NN * 4);
  int* maskI = (int*)take(NN * 4);
  float* s_hq = (float*)take(NN * 4);
  float* cntq = (float*)take(NN * 4);
  float* s_hgq = (float*)take(NN * 4);
  float* scal = (float*)take(64 * 4);
  int* qcnt = (int*)take(24 * QPAD * 4);
  size_t zero_end = off;
  // ---- non-zeroed scratch ----
  unsigned short* slotsA = (unsigned short*)take((size_t)NN * CAP * 2);
  unsigned short* slotsB = (unsigned short*)take((size_t)NN * CAP * 2);
  unsigned short* slotsC = (unsigned short*)take((size_t)NN * CAP * 2);
  unsigned int* qdata = (unsigned int*)take((size_t)24 * QCAP * 4);
  float* dinv = (float*)take(NN * 4);
  float* Binv = (float*)take(NN * 4);
  float* Dninv = (float*)take(NN * 4);
  float4* simbuf = (float4*)take((size_t)NN * 16);
  unsigned short* Wpack = (unsigned short*)take((size_t)7 * 16384 * 2);
  const size_t BFSZ = (size_t)NN * HH * 2;
  unsigned short* B0 = (unsigned short*)take(BFSZ);
  unsigned short* B1 = (unsigned short*)take(BFSZ);
  unsigned short* B2 = (unsigned short*)take(BFSZ);
  unsigned short* B3 = (unsigned short*)take(BFSZ);
  unsigned short* B4 = (unsigned short*)take(BFSZ);
  unsigned short* B5 = (unsigned short*)take(BFSZ);
  unsigned short* B6 = (unsigned short*)take(BFSZ);  // feats2 bf16
  unsigned char* P1 = (unsigned char*)take((size_t)NN * 256);  // fp8 pair [node][2][128]
  unsigned char* P2 = (unsigned char*)take((size_t)NN * 256);
  unsigned char* P3 = (unsigned char*)take((size_t)NN * 256);

  const int EB = (EE + 255) / 256;
  const int GMB = (NN + 63) / 64;    // gemm blocks (64 rows each)
  const int GTB = (NN + 7) / 8;      // gather blocks (8 nodes/block, 32 lanes/node)
  const int RB = (NN + 3) / 4;       // row-wave blocks
  const short8* Wp = (const short8*)Wpack;

  hipMemsetAsync(d_ws, 0, zero_end, stream);
  pack_k<<<(7 * 2048 + 255) / 256, 256, 0, stream>>>(W0, Wh0, Wlf, Wf0, Wfh0, Wm1, Wm2,
                                                     Wpack);
  // radix fill: bin edges once into (role x partition) queues, then LDS-cursor fill
  // (derive folded into fillp; maskI setup folded into bin block 0)
  bin_k<<<BINB, 256, 0, stream>>>(ei, ea, qcnt, qdata, pos, qp, maskI);
  fillp_k<<<24 * WSUB, 256, 0, stream>>>(qcnt, qdata, cursor3, slotsA, slotsB, slotsC,
                                         cntq, qp, dinv, Binv, Dninv);
  // feats @ {W0, Wh0, Wlf}: xw0 -> P1.half0 (fp8), xwh -> P2.half0 (fp8), feats2 -> B6 bf16
  gemm3_mfma<<<2 * GMB, 256, 0, stream>>>(feats, Wp, blf, P1, P2, B6, NN);
  // fused {shq | fuse2}: both ready after fillp+gemm3
  f2_k<<<EB + RB, 256, 0, stream>>>(ei, ea, qp, dinv, Binv, cntq, s_hq, s_hgq, B6, Wlq,
                                    blq, aq_, a_, ahq_, ah_, B3, B4, EB);
  // xwf -> P1.half1 ; xwfh -> P2.half1  (fp8, batched)
  gemm2_mfma<false, false, 2><<<2 * GMB, 256, 0, stream>>>(
      B3, B4, Wp + (size_t)3 * 2048, Wp + (size_t)4 * 2048, nullptr, nullptr, P1 + 128,
      P2 + 128, NN, GMB);
  // gathers: pass1 GCN P1 -> (B0=g0, B1=gf) bf16 ; pass2 HG-he P2 -> P3 fp8  [merged]
  dgather12_k<<<2 * GTB, 256, 0, stream>>>((const uint2*)P1, B0, B1, (const uint2*)P2,
                                           (uint2*)P3, cursor3, slotsA, slotsB, dinv, Binv,
                                           GTB);
  // pass3 HG-node P3 -> (B2, B5) bf16
  dgather3_k<<<GTB, 256, 0, stream>>>((const uint2*)P3, B2, B5, cursor3, slotsC, Dninv);
  // hf = B3 ; h_augf = B4  (batched fuse+residual+relu; B3/B4 free after gemm2 above)
  fuse_add2_k<<<2 * RB, 256, 0, stream>>>(
      B0, B1, s_hq, nullptr, Wq0, bq0, b0, aq0, a0, bf0, B3,
      B2, B5, s_hgq, Dninv, Whq0, bhq0, bh0, ahq0, ah0, bfh0, B4, RB);
  // MLPs (batched per layer): L1: (B3->B0),(B4->B1) ; L2: (B0->B2=z),(B1->B5=z_aug) bf16
  gemm2_mfma<true, true, 1><<<2 * GMB, 256, 0, stream>>>(
      B3, B4, Wp + (size_t)5 * 2048, Wp + (size_t)5 * 2048, bm1, bm1, B0, B1, NN, GMB);
  gemm2_mfma<true, false, 1><<<2 * GMB, 256, 0, stream>>>(
      B0, B1, Wp + (size_t)6 * 2048, Wp + (size_t)6 * 2048, bm2, bm2, B2, B5, NN, GMB);
  // loss
  sim_k<<<RB, 256, 0, stream>>>(B2, B5, qp, simbuf, scal);
  reduce_sim_k<<<64, 256, 0, stream>>>(simbuf, maskI, scal);
  final_k<<<1, 64, 0, stream>>>(scal, (float*)d_out);
}

// Round 12
// 405.836 us; speedup vs baseline: 1.0596x; 1.0373x over previous
//
#include <hip/hip_runtime.h>

#define NN 50000
#define EE 600000
#define HH 128
#define TAU_INV 2.0f   // 1/TAU, TAU=0.5
#define PSZ 6250       // NN / 8 partitions (partition <-> XCD fixed bijection)
#define CAP 48         // bucket capacity; max degree for multinomial(600k,1/50k) ~ 36

// radix-fill parameters
#define BINB 512                         // bin_k blocks
#define BUFC 240                         // per-(role,part) LDS buffer cap per BLOCK
#define QCAP 80000                       // per-(role,part) queue cap (mean 75000, +19 sigma)
#define QPAD 16                          // qcnt stride (ints) -> one counter per 64B line
#define WSUB 32                          // sub-ranges per (role,partition)
#define SUBN 196                         // ceil(PSZ/WSUB)

typedef __attribute__((ext_vector_type(8))) short short8;
typedef __attribute__((ext_vector_type(4))) float f32x4;
typedef __attribute__((ext_vector_type(2))) float floatx2;

// ---------- helpers ----------
__device__ __forceinline__ float wsum64(float v) {
#pragma unroll
  for (int m = 32; m >= 1; m >>= 1) v += __shfl_xor(v, m, 64);
  return v;
}
__device__ __forceinline__ unsigned short f2bf(float f) {
  unsigned u = __builtin_bit_cast(unsigned, f);
  u = u + 0x7FFFu + ((u >> 16) & 1u);
  return (unsigned short)(u >> 16);
}
__device__ __forceinline__ float bf2f(unsigned short h) {
  unsigned u = ((unsigned)h) << 16;
  return __builtin_bit_cast(float, u);
}
// fp8 e4m3 (OCP) via gfx950 HW converts
__device__ __forceinline__ unsigned char fp8_enc1(float v) {
  int p = __builtin_amdgcn_cvt_pk_fp8_f32(v, v, 0, false);
  return (unsigned char)(p & 0xFF);
}
__device__ __forceinline__ void fp8x8_dec(uint2 v, float* f) {
  floatx2 a = __builtin_amdgcn_cvt_pk_f32_fp8(v.x, false);
  floatx2 b = __builtin_amdgcn_cvt_pk_f32_fp8(v.x, true);
  floatx2 c = __builtin_amdgcn_cvt_pk_f32_fp8(v.y, false);
  floatx2 d = __builtin_amdgcn_cvt_pk_f32_fp8(v.y, true);
  f[0] = a.x; f[1] = a.y; f[2] = b.x; f[3] = b.y;
  f[4] = c.x; f[5] = c.y; f[6] = d.x; f[7] = d.y;
}
__device__ __forceinline__ uint2 fp8x8_enc(const float* f) {
  int w0 = __builtin_amdgcn_cvt_pk_fp8_f32(f[0], f[1], 0, false);
  w0 = __builtin_amdgcn_cvt_pk_fp8_f32(f[2], f[3], w0, true);
  int w1 = __builtin_amdgcn_cvt_pk_fp8_f32(f[4], f[5], 0, false);
  w1 = __builtin_amdgcn_cvt_pk_fp8_f32(f[6], f[7], w1, true);
  return make_uint2((unsigned)w0, (unsigned)w1);
}

#define LDSW 136  // 128 + 8 bf16 pad

// ---------- phase 1: bin edges into (role x partition) queues ----------
// Reads each edge ONCE; grid-stride accumulation into LDS with no intermediate
// barriers; ONE global alloc atomic per (block,group); flattened prefix copy-out.
// Block 0 also does maskI setup.
// role 0: key=dst, pay=src (GCN)   role 1: key=he, pay=node   role 2: key=node, pay=he
__global__ __launch_bounds__(256) void bin_k(const int* __restrict__ ei,
                                             const int* __restrict__ ea,
                                             int* __restrict__ qcnt,
                                             unsigned int* __restrict__ qdata,
                                             const int* __restrict__ pos,
                                             const int* __restrict__ qp,
                                             int* __restrict__ maskI) {
  __shared__ int cnt[24], base[24], pfx[25];
  __shared__ unsigned int buf[24 * BUFC];
  const int tid = threadIdx.x;
  if (tid < 24) cnt[tid] = 0;
  if (blockIdx.x == 0 && tid < 100) maskI[pos[tid]] = 1;
  __syncthreads();
  if (blockIdx.x == 0 && tid == 0) maskI[*qp] = 0;
  for (int e = blockIdx.x * 256 + tid; e < EE; e += BINB * 256) {
    int pay0 = __builtin_nontemporal_load(ei + e);      // src
    int k0 = __builtin_nontemporal_load(ei + EE + e);   // dst
    int pay1 = __builtin_nontemporal_load(ea + e);      // node
    int k1 = __builtin_nontemporal_load(ea + EE + e);   // he
    int k2 = pay1, pay2 = k1;
    int g0 = k0 / PSZ;
    int g1 = 8 + k1 / PSZ;
    int g2 = 16 + k2 / PSZ;
    int o0 = atomicAdd(&cnt[g0], 1);
    int o1 = atomicAdd(&cnt[g1], 1);
    int o2 = atomicAdd(&cnt[g2], 1);
    if (o0 < BUFC) buf[g0 * BUFC + o0] = ((unsigned)k0 << 16) | (unsigned)pay0;
    if (o1 < BUFC) buf[g1 * BUFC + o1] = ((unsigned)k1 << 16) | (unsigned)pay1;
    if (o2 < BUFC) buf[g2 * BUFC + o2] = ((unsigned)k2 << 16) | (unsigned)pay2;
  }
  __syncthreads();
  if (tid < 24) {
    int c = min(cnt[tid], BUFC);
    cnt[tid] = c;
    base[tid] = atomicAdd(&qcnt[tid * QPAD], c);  // padded: 1 counter per 64B line
  }
  __syncthreads();
  if (tid == 0) {
    int s = 0;
#pragma unroll
    for (int g = 0; g < 24; ++g) { pfx[g] = s; s += cnt[g]; }
    pfx[24] = s;
  }
  __syncthreads();
  const int total = pfx[24];
  for (int j = tid; j < total; j += 256) {
    int lo2 = 0, hi2 = 24;
    while (lo2 + 1 < hi2) {
      int mid = (lo2 + hi2) >> 1;
      if (j >= pfx[mid]) lo2 = mid; else hi2 = mid;
    }
    int g = lo2;
    int i = j - pfx[g];
    int dq = base[g] + i;
    if (dq < QCAP) qdata[(size_t)g * QCAP + dq] = buf[g * BUFC + i];
  }
}

// ---------- phase 2: partitioned fill with LDS cursors (+ fused derive) ----------
__global__ __launch_bounds__(256) void fillp_k(const int* __restrict__ qcnt,
                                               const unsigned int* __restrict__ qdata,
                                               int* __restrict__ cursor,
                                               unsigned short* __restrict__ slotsA,
                                               unsigned short* __restrict__ slotsB,
                                               unsigned short* __restrict__ slotsC,
                                               float* __restrict__ cntq,
                                               const int* __restrict__ qp,
                                               float* __restrict__ dinv,
                                               float* __restrict__ Binv,
                                               float* __restrict__ Dninv) {
  __shared__ int cur[SUBN];
  const int w = blockIdx.x;  // 0..767
  const int p = w & 7;
  const int r = (w >> 3) % 3;
  const int s = w / 24;
  const int lo = p * PSZ + s * SUBN;
  const int hi = min(lo + SUBN, (p + 1) * PSZ);
  const int tid = threadIdx.x;
  if (tid < SUBN) cur[tid] = 0;
  __syncthreads();
  const int g = r * 8 + p;
  const int qlen = min(qcnt[g * QPAD], QCAP);
  const unsigned int* qd = qdata + (size_t)g * QCAP;
  unsigned short* slots = (r == 0) ? slotsA : (r == 1) ? slotsB : slotsC;
  const int q = *qp;
  auto proc = [&](unsigned int rec) {
    int key = (int)(rec >> 16);
    if (key >= lo && key < hi) {
      int pay = (int)(rec & 0xFFFFu);
      int idx = atomicAdd(&cur[key - lo], 1);
      if (idx < CAP) slots[key * CAP + idx] = (unsigned short)pay;
      if (r == 1 && pay == q) atomicAdd(&cntq[key], 1.0f);
    }
  };
  const int nv4 = qlen >> 2;
  const uint4* qd4 = (const uint4*)qd;
  int j = tid;
  for (; j + 256 < nv4; j += 512) {
    uint4 r0 = qd4[j];
    uint4 r1 = qd4[j + 256];
    proc(r0.x); proc(r0.y); proc(r0.z); proc(r0.w);
    proc(r1.x); proc(r1.y); proc(r1.z); proc(r1.w);
  }
  if (j < nv4) {
    uint4 r0 = qd4[j];
    proc(r0.x); proc(r0.y); proc(r0.z); proc(r0.w);
  }
  int i = (nv4 << 2) + tid;
  if (i < qlen) proc(qd[i]);
  __syncthreads();
  for (int k = lo + tid; k < hi; k += 256) {
    int c = cur[k - lo];
    cursor[r * NN + k] = c;
    if (r == 0) dinv[k] = rsqrtf((float)(c + 1));            // deg incl. self-loop
    else if (r == 1) Binv[k] = (c > 0) ? 1.0f / (float)c : 0.0f;
    else Dninv[k] = (c > 0) ? 1.0f / (float)c : 0.0f;
  }
}

// ---------- shq body: analytic query coefficients ----------
__device__ __forceinline__ void shq_body(const int* __restrict__ ei, const int* __restrict__ ea,
                                         const int* __restrict__ qp,
                                         const float* __restrict__ dinv,
                                         const float* __restrict__ Binv,
                                         const float* __restrict__ cntq,
                                         float* __restrict__ s_hq, float* __restrict__ s_hgq,
                                         int bid) {
  int e = bid * 256 + threadIdx.x;
  if (e >= EE) return;
  int q = *qp;
  int src = __builtin_nontemporal_load(ei + e);
  if (src == q) {
    int dst = __builtin_nontemporal_load(ei + EE + e);
    atomicAdd(&s_hq[dst], dinv[q] * dinv[dst]);
  }
  int he = __builtin_nontemporal_load(ea + EE + e);
  float cq = cntq[he];
  if (cq != 0.0f) {
    int node = __builtin_nontemporal_load(ea + e);
    atomicAdd(&s_hgq[node], Binv[he] * cq);
  }
  if (e == 0) atomicAdd(&s_hq[q], dinv[q] * dinv[q]);  // self-loop of query gcn
}

// ---------- fuse2 body: hf_ and hfh_ from analytic querys2 and feats2(bf16) ----------
__device__ __forceinline__ void fuse2_body(const unsigned short* __restrict__ f2,
                                           const int* __restrict__ qp,
                                           const float* __restrict__ Wlq,
                                           const float* __restrict__ blq,
                                           const float* __restrict__ aq1,
                                           const float* __restrict__ a1,
                                           const float* __restrict__ aq2,
                                           const float* __restrict__ a2,
                                           unsigned short* __restrict__ out1,
                                           unsigned short* __restrict__ out2, int bid) {
  int row = bid * 4 + (threadIdx.x >> 6);
  if (row >= NN) return;
  int lane = threadIdx.x & 63;
  int c0 = lane, c1 = lane + 64;
  int q = *qp;
  float q20 = blq[c0] + ((row == q) ? Wlq[c0] : 0.f);
  float q21 = blq[c1] + ((row == q) ? Wlq[c1] : 0.f);
  float f0 = bf2f(f2[(size_t)row * 128 + c0]);
  float f1 = bf2f(f2[(size_t)row * 128 + c1]);
  float dq1 = wsum64(q20 * aq1[c0] + q21 * aq1[c1]);
  float df1 = wsum64(f0 * a1[c0] + f1 * a1[c1]);
  float dq2 = wsum64(q20 * aq2[c0] + q21 * aq2[c1]);
  float df2 = wsum64(f0 * a2[c0] + f1 * a2[c1]);
  {
    float mx = fmaxf(dq1, df1);
    float e0 = expf(dq1 - mx), e1 = expf(df1 - mx);
    float w0 = e0 / (e0 + e1), w1 = 1.f - w0;
    out1[(size_t)row * 128 + c0] = f2bf(w0 * q20 + w1 * f0);
    out1[(size_t)row * 128 + c1] = f2bf(w0 * q21 + w1 * f1);
  }
  {
    float mx = fmaxf(dq2, df2);
    float e0 = expf(dq2 - mx), e1 = expf(df2 - mx);
    float w0 = e0 / (e0 + e1), w1 = 1.f - w0;
    out2[(size_t)row * 128 + c0] = f2bf(w0 * q20 + w1 * f0);
    out2[(size_t)row * 128 + c1] = f2bf(w0 * q21 + w1 * f1);
  }
}

// ---------- fused f2: {shq | fuse2} ----------
__global__ __launch_bounds__(256) void f2_k(const int* __restrict__ ei,
                                            const int* __restrict__ ea,
                                            const int* __restrict__ qp,
                                            const float* __restrict__ dinv,
                                            const float* __restrict__ Binv,
                                            const float* __restrict__ cntq,
                                            float* __restrict__ s_hq,
                                            float* __restrict__ s_hgq,
                                            const unsigned short* __restrict__ B6,
                                            const float* __restrict__ Wlq,
                                            const float* __restrict__ blq,
                                            const float* __restrict__ aq_,
                                            const float* __restrict__ a_,
                                            const float* __restrict__ ahq_,
                                            const float* __restrict__ ah_,
                                            unsigned short* __restrict__ B3,
                                            unsigned short* __restrict__ B4, int eb) {
  int b = blockIdx.x;
  if (b < eb)
    shq_body(ei, ea, qp, dinv, Binv, cntq, s_hq, s_hgq, b);
  else
    fuse2_body(B6, qp, Wlq, blq, aq_, a_, ahq_, ah_, B3, B4, b - eb);
}

// ---------- pack 7 weight matrices into MFMA B-fragment order ----------
__global__ void pack_k(const float* __restrict__ W0, const float* __restrict__ Wh0,
                       const float* __restrict__ Wlf, const float* __restrict__ Wf0,
                       const float* __restrict__ Wfh0, const float* __restrict__ Wm1,
                       const float* __restrict__ Wm2, unsigned short* __restrict__ out) {
  int tid = blockIdx.x * 256 + threadIdx.x;
  if (tid >= 7 * 2048) return;
  int mat = tid >> 11, r = tid & 2047;
  int s = r >> 9, c = (r >> 6) & 7, lane = r & 63;
  const float* W = (mat == 0) ? W0 : (mat == 1) ? Wh0 : (mat == 2) ? Wlf
                 : (mat == 3) ? Wf0 : (mat == 4) ? Wfh0 : (mat == 5) ? Wm1 : Wm2;
  int k0 = 32 * s + (lane >> 4) * 8;
  int n = 16 * c + (lane & 15);
  unsigned short* o = out + (size_t)tid * 8;
#pragma unroll
  for (int j = 0; j < 8; ++j) o[j] = f2bf(W[(k0 + j) * 128 + n]);
}

// ---------- gemm core (A staged in LDS as bf16; LDS-staged coalesced epilogue) ----------
// OM: 1 = bf16 out (ushort stride 128), 2 = fp8 out (uchar stride 256).
template <bool BIAS, bool RELU, int OM>
__device__ __forceinline__ void gemm_core(unsigned short* As, const short8* Wp,
                                          const float* bias, void* outv, int r0, int nrows,
                                          int tid) {
  const int wave = tid >> 6, lane = tid & 63;
  const int quad = lane >> 4, l15 = lane & 15;
  f32x4 acc[8];
#pragma unroll
  for (int c = 0; c < 8; ++c) acc[c] = (f32x4){0.f, 0.f, 0.f, 0.f};
#pragma unroll
  for (int s = 0; s < 4; ++s) {
    short8 a = *(const short8*)&As[(wave * 16 + l15) * LDSW + s * 32 + quad * 8];
#pragma unroll
    for (int c = 0; c < 8; ++c) {
      short8 b = Wp[(s * 8 + c) * 64 + lane];
      acc[c] = __builtin_amdgcn_mfma_f32_16x16x32_bf16(a, b, acc[c], 0, 0, 0);
    }
  }
  __syncthreads();  // all waves done reading As before overwrite
  const int rwl = wave * 16 + quad * 4;  // local row base
  if (OM == 2) {
    unsigned char* l8 = (unsigned char*)As;  // [64][128] fp8 = 8KB
#pragma unroll
    for (int c = 0; c < 8; ++c) {
      int col = c * 16 + l15;
      float bv = BIAS ? bias[col] : 0.f;
#pragma unroll
      for (int r = 0; r < 4; ++r) {
        float v = acc[c][r] + bv;
        if (RELU) v = fmaxf(v, 0.f);
        l8[(rwl + r) * 128 + col] = fp8_enc1(v);
      }
    }
    __syncthreads();
#pragma unroll
    for (int t = 0; t < 2; ++t) {
      int idx = (t * 256 + tid) * 16;  // 0..8191
      int row = idx >> 7, off = idx & 127;
      int grow = r0 + row;
      if (grow < nrows)
        *(uint4*)&((unsigned char*)outv)[(size_t)grow * 256 + off] = *(uint4*)&l8[idx];
    }
  } else {
    unsigned short* l16 = As;  // [64][128] ushort = 16KB
#pragma unroll
    for (int c = 0; c < 8; ++c) {
      int col = c * 16 + l15;
      float bv = BIAS ? bias[col] : 0.f;
#pragma unroll
      for (int r = 0; r < 4; ++r) {
        float v = acc[c][r] + bv;
        if (RELU) v = fmaxf(v, 0.f);
        l16[(rwl + r) * 128 + col] = f2bf(v);
      }
    }
    __syncthreads();
#pragma unroll
    for (int t = 0; t < 4; ++t) {
      int idx = (t * 256 + tid) * 16;  // byte idx 0..16383
      int row = idx >> 8, off = idx & 255;
      int grow = r0 + row;
      if (grow < nrows)
        *(uint4*)&((unsigned char*)outv)[(size_t)grow * 256 + off] =
            *(uint4*)&((unsigned char*)l16)[idx];
    }
  }
}

__device__ __forceinline__ void stage_bf16(const unsigned short* A, unsigned short* As,
                                           int r0, int nrows, int tid) {
#pragma unroll
  for (int t = 0; t < 4; ++t) {
    int v = t * 256 + tid;
    int row = v >> 4, cc = v & 15;
    int gr = r0 + row;
    uint4 val = make_uint4(0, 0, 0, 0);
    if (gr < nrows) val = ((const uint4*)A)[(size_t)gr * 16 + cc];
    *(uint4*)&As[row * LDSW + cc * 8] = val;
  }
}

// ---------- batched pair GEMM: two independent A@W ----------
template <bool BIAS, bool RELU, int OM>
__global__ __launch_bounds__(256) void gemm2_mfma(const unsigned short* __restrict__ A0,
                                                  const unsigned short* __restrict__ A1,
                                                  const short8* __restrict__ Wp0,
                                                  const short8* __restrict__ Wp1,
                                                  const float* __restrict__ b0,
                                                  const float* __restrict__ b1,
                                                  void* __restrict__ o0, void* __restrict__ o1,
                                                  int nrows, int nblk) {
  __shared__ unsigned short As[64 * LDSW];
  int b = blockIdx.x;
  const unsigned short* A = A0;
  const short8* Wp = Wp0;
  const float* bias = b0;
  void* o = o0;
  if (b >= nblk) {
    b -= nblk; A = A1; Wp = Wp1; bias = b1; o = o1;
  }
  const int r0 = b * 64;
  stage_bf16(A, As, r0, nrows, threadIdx.x);
  __syncthreads();
  gemm_core<BIAS, RELU, OM>(As, Wp, bias, o, r0, nrows, threadIdx.x);
}

// ---------- 3 GEMMs sharing one fp32-A tile; column-halved for occupancy ----------
__global__ __launch_bounds__(256) void gemm3_mfma(const float* __restrict__ A,
                                                  const short8* __restrict__ Wp,  // mats 0,1,2
                                                  const float* __restrict__ bias2,
                                                  unsigned char* __restrict__ p1,
                                                  unsigned char* __restrict__ p2,
                                                  unsigned short* __restrict__ out2,
                                                  int nrows) {
  __shared__ unsigned short As[64 * LDSW];
  const int tid = threadIdx.x;
  const int bh = blockIdx.x & 1;
  const int r0 = (blockIdx.x >> 1) * 64;
#pragma unroll
  for (int t = 0; t < 8; ++t) {
    int v = t * 256 + tid;
    int row = v >> 5, c4 = v & 31;  // float4 chunk
    int gr = r0 + row;
    f32x4 val = (f32x4){0.f, 0.f, 0.f, 0.f};
    if (gr < nrows) val = ((const f32x4*)A)[(size_t)gr * 32 + c4];  // plain: L3 reuse
    ushort4 o;
    o.x = f2bf(val.x); o.y = f2bf(val.y); o.z = f2bf(val.z); o.w = f2bf(val.w);
    *(ushort4*)&As[row * LDSW + c4 * 4] = o;
  }
  __syncthreads();
  const int wave = tid >> 6, lane = tid & 63;
  const int quad = lane >> 4, l15 = lane & 15;
  f32x4 acc[3][4];
#pragma unroll
  for (int m = 0; m < 3; ++m)
#pragma unroll
    for (int c = 0; c < 4; ++c) acc[m][c] = (f32x4){0.f, 0.f, 0.f, 0.f};
#pragma unroll
  for (int s = 0; s < 4; ++s) {
    short8 a = *(const short8*)&As[(wave * 16 + l15) * LDSW + s * 32 + quad * 8];
#pragma unroll
    for (int m = 0; m < 3; ++m)
#pragma unroll
      for (int c = 0; c < 4; ++c) {
        short8 bb = Wp[(size_t)m * 2048 + (s * 8 + bh * 4 + c) * 64 + lane];
        acc[m][c] = __builtin_amdgcn_mfma_f32_16x16x32_bf16(a, bb, acc[m][c], 0, 0, 0);
      }
  }
  __syncthreads();  // done reading As
  // stage outputs: P1 [64][64]B @0, P2 @4096, B6 [64][64]ushort @8192 (16KB total)
  unsigned char* l8a = (unsigned char*)As;
  unsigned char* l8b = l8a + 4096;
  unsigned short* l16 = (unsigned short*)(l8a + 8192);
  const int rwl = wave * 16 + quad * 4;
#pragma unroll
  for (int c = 0; c < 4; ++c) {
    int coll = c * 16 + l15;                 // local col 0..63
    float bv = bias2[(bh * 4 + c) * 16 + l15];
#pragma unroll
    for (int r = 0; r < 4; ++r) {
      int lrow = rwl + r;
      l8a[lrow * 64 + coll] = fp8_enc1(acc[0][c][r]);
      l8b[lrow * 64 + coll] = fp8_enc1(acc[1][c][r]);
      l16[lrow * 64 + coll] = f2bf(acc[2][c][r] + bv);
    }
  }
  __syncthreads();
  {  // P1/P2: 4KB each, 16B per thread, rows are 64B-contiguous chunks
    int idx = tid * 16;
    int row = idx >> 6, off = idx & 63;
    int grow = r0 + row;
    if (grow < nrows) {
      *(uint4*)&p1[(size_t)grow * 256 + bh * 64 + off] = *(uint4*)&l8a[idx];
      *(uint4*)&p2[(size_t)grow * 256 + bh * 64 + off] = *(uint4*)&l8b[idx];
    }
  }
#pragma unroll
  for (int t = 0; t < 2; ++t) {  // B6: 8KB, rows are 128B-contiguous chunks
    int idx = (t * 256 + tid) * 16;
    int row = idx >> 7, off = idx & 127;
    int grow = r0 + row;
    if (grow < nrows)
      *(uint4*)&((unsigned char*)out2)[(size_t)grow * 256 + bh * 128 + off] =
          *(uint4*)&((unsigned char*)l16)[idx];
  }
}

// ---------- paired gather (bucket CSR), fp8-pair input, 4x-unrolled (R8 structure) ------
// OUT 0: fp8-pair out (yp).  OUT 2: FUSED fuse_add epilogue -> bf16 out (outf).
// Fused epilogue: 32-lane group holds y1 (lanes 0-15) and y2 (lanes 16-31) of the SAME
// node; shfl_xor(16) aligns y2 with y1 cols, 16-lane reduce gives attention logits,
// result written directly — eliminates the fuse_add2_k round-trip (B0/B1/B2/B5).
// MODE 0: y[i] = wv[i]*(wv[i]*x[i] + sum_s wv[s]*x[s])   (GCN w/ self-loop)
// MODE 1: y[i] = wv[i]*sum_s x[s]                         (hypergraph halves)
template <int MODE, int OUT>
__device__ __forceinline__ void gpair_body(const uint2* __restrict__ xp,
                                           uint2* __restrict__ yp,
                                           unsigned short* __restrict__ outf,
                                           const int* __restrict__ cnt,
                                           const unsigned short* __restrict__ slots,
                                           const float* __restrict__ wv,
                                           const float* __restrict__ svec,
                                           const float* __restrict__ Wq,
                                           const float* __restrict__ bq,
                                           const float* __restrict__ bm,
                                           const float* __restrict__ aq,
                                           const float* __restrict__ am,
                                           const float* __restrict__ bres, int blk) {
  int node = blk * 8 + (threadIdx.x >> 5);
  if (node >= NN) return;
  int l = threadIdx.x & 31;
  int st = node * CAP;
  int n = min(cnt[node], CAP);
  float acc[8];
#pragma unroll
  for (int i = 0; i < 8; ++i) acc[i] = 0.f;
  int p = 0;
  for (; p + 4 <= n; p += 4) {
    ushort4 s4 = *(const ushort4*)&slots[st + p];
    uint2 v0 = xp[(size_t)s4.x * 32 + l];
    uint2 v1 = xp[(size_t)s4.y * 32 + l];
    uint2 v2 = xp[(size_t)s4.z * 32 + l];
    uint2 v3 = xp[(size_t)s4.w * 32 + l];
    float f[8];
    if (MODE == 0) {
      float w0 = wv[s4.x], w1 = wv[s4.y], w2 = wv[s4.z], w3 = wv[s4.w];
      fp8x8_dec(v0, f);
#pragma unroll
      for (int i = 0; i < 8; ++i) acc[i] = fmaf(w0, f[i], acc[i]);
      fp8x8_dec(v1, f);
#pragma unroll
      for (int i = 0; i < 8; ++i) acc[i] = fmaf(w1, f[i], acc[i]);
      fp8x8_dec(v2, f);
#pragma unroll
      for (int i = 0; i < 8; ++i) acc[i] = fmaf(w2, f[i], acc[i]);
      fp8x8_dec(v3, f);
#pragma unroll
      for (int i = 0; i < 8; ++i) acc[i] = fmaf(w3, f[i], acc[i]);
    } else {
      fp8x8_dec(v0, f);
#pragma unroll
      for (int i = 0; i < 8; ++i) acc[i] += f[i];
      fp8x8_dec(v1, f);
#pragma unroll
      for (int i = 0; i < 8; ++i) acc[i] += f[i];
      fp8x8_dec(v2, f);
#pragma unroll
      for (int i = 0; i < 8; ++i) acc[i] += f[i];
      fp8x8_dec(v3, f);
#pragma unroll
      for (int i = 0; i < 8; ++i) acc[i] += f[i];
    }
  }
  for (; p < n; ++p) {
    int s = slots[st + p];
    uint2 v = xp[(size_t)s * 32 + l];
    float f[8];
    fp8x8_dec(v, f);
    if (MODE == 0) {
      float w = wv[s];
#pragma unroll
      for (int i = 0; i < 8; ++i) acc[i] = fmaf(w, f[i], acc[i]);
    } else {
#pragma unroll
      for (int i = 0; i < 8; ++i) acc[i] += f[i];
    }
  }
  float sc = wv[node];
  if (MODE == 0) {
    uint2 v = xp[(size_t)node * 32 + l];
    float f[8];
    fp8x8_dec(v, f);
#pragma unroll
    for (int i = 0; i < 8; ++i) acc[i] = sc * fmaf(sc, f[i], acc[i]);
  } else {
#pragma unroll
    for (int i = 0; i < 8; ++i) acc[i] *= sc;
  }
  if (OUT == 0) {
    yp[(size_t)node * 32 + l] = fp8x8_enc(acc);
  } else {
    // ---- fused fuse_add epilogue ----
    float y2v[8];
#pragma unroll
    for (int i = 0; i < 8; ++i) y2v[i] = __shfl_xor(acc[i], 16, 64);
    float s = svec[node];
    if (MODE == 1) s *= sc;  // dscale = Dninv = wv for HG side
    int cg = l & 15;
    float h[8], hq[8];
    float pdm = 0.f, pdq = 0.f;
#pragma unroll
    for (int i = 0; i < 8; ++i) {
      int c = cg * 8 + i;
      h[i] = fmaxf(acc[i] + bm[c], 0.f);
      hq[i] = fmaxf(fmaf(s, Wq[c], bq[c]), 0.f);
      pdm = fmaf(h[i], am[c], pdm);
      pdq = fmaf(hq[i], aq[c], pdq);
    }
#pragma unroll
    for (int m = 1; m <= 8; m <<= 1) {  // reduce within 16-lane subgroup
      pdm += __shfl_xor(pdm, m, 64);
      pdq += __shfl_xor(pdq, m, 64);
    }
    float mx = fmaxf(pdq, pdm);
    float e0 = expf(pdq - mx), e1 = expf(pdm - mx);
    float w0 = e0 / (e0 + e1), w1 = 1.f - w0;
    if (l < 16) {  // lanes 16-31 hold garbage (y2-based) partials; masked out
      unsigned short r[8];
#pragma unroll
      for (int i = 0; i < 8; ++i) {
        int c = cg * 8 + i;
        r[i] = f2bf(fmaxf(fmaf(w0, hq[i], fmaf(w1, h[i], y2v[i] + bres[c])), 0.f));
      }
      uint4 o;
      o.x = ((unsigned)r[1] << 16) | r[0];
      o.y = ((unsigned)r[3] << 16) | r[2];
      o.z = ((unsigned)r[5] << 16) | r[4];
      o.w = ((unsigned)r[7] << 16) | r[6];
      *(uint4*)&outf[(size_t)node * 128 + cg * 8] = o;
    }
  }
}

// merged: pass1 (GCN + fused epilogue -> B3) + pass2 (HG-he, fp8-pair out -> P3)
__global__ void dgather12_k(const uint2* __restrict__ xp1, unsigned short* __restrict__ B3,
                            const uint2* __restrict__ xp2, uint2* __restrict__ yp3,
                            const int* __restrict__ cursor,
                            const unsigned short* __restrict__ slotsA,
                            const unsigned short* __restrict__ slotsB,
                            const float* __restrict__ dinv, const float* __restrict__ Binv,
                            const float* __restrict__ s_hq, const float* __restrict__ Wq0,
                            const float* __restrict__ bq0, const float* __restrict__ b0,
                            const float* __restrict__ aq0, const float* __restrict__ a0,
                            const float* __restrict__ bf0, int nblk) {
  int b = blockIdx.x;
  if (b < nblk)
    gpair_body<0, 2>(xp1, nullptr, B3, cursor, slotsA, dinv, s_hq, Wq0, bq0, b0, aq0, a0,
                     bf0, b);
  else
    gpair_body<1, 0>(xp2, yp3, nullptr, cursor + NN, slotsB, Binv, nullptr, nullptr,
                     nullptr, nullptr, nullptr, nullptr, nullptr, b - nblk);
}

// pass3: HG-node gather + fused epilogue -> B4
__global__ void dgather3_k(const uint2* __restrict__ xp, unsigned short* __restrict__ B4,
                           const int* __restrict__ cursor,
                           const unsigned short* __restrict__ slotsC,
                           const float* __restrict__ Dninv, const float* __restrict__ s_hgq,
                           const float* __restrict__ Whq0, const float* __restrict__ bhq0,
                           const float* __restrict__ bh0, const float* __restrict__ ahq0,
                           const float* __restrict__ ah0, const float* __restrict__ bfh0) {
  gpair_body<1, 2>(xp, nullptr, B4, cursor + 2 * NN, slotsC, Dninv, s_hgq, Whq0, bhq0, bh0,
                   ahq0, ah0, bfh0, blockIdx.x);
}

// ---------- per-row cosine logits (bf16 z, q-norms computed locally) ----------
__global__ void sim_k(const unsigned short* __restrict__ z,
                      const unsigned short* __restrict__ za, const int* __restrict__ qp,
                      float4* __restrict__ simbuf, float* __restrict__ scal_out) {
  int row = blockIdx.x * 4 + (threadIdx.x >> 6);
  if (row >= NN) return;
  int lane = threadIdx.x & 63;
  int c0 = lane, c1 = lane + 64;
  int q = *qp;
  float zi0 = bf2f(z[(size_t)row * 128 + c0]), zi1 = bf2f(z[(size_t)row * 128 + c1]);
  float zai0 = bf2f(za[(size_t)row * 128 + c0]), zai1 = bf2f(za[(size_t)row * 128 + c1]);
  float zq0 = bf2f(z[(size_t)q * 128 + c0]), zq1 = bf2f(z[(size_t)q * 128 + c1]);
  float zaq0 = bf2f(za[(size_t)q * 128 + c0]), zaq1 = bf2f(za[(size_t)q * 128 + c1]);
  float nzi = wsum64(zi0 * zi0 + zi1 * zi1);
  float nzai = wsum64(zai0 * zai0 + zai1 * zai1);
  float nzq = wsum64(zq0 * zq0 + zq1 * zq1);
  float nzaq = wsum64(zaq0 * zaq0 + zaq1 * zaq1);
  float d1 = wsum64(zi0 * zq0 + zi1 * zq1);
  float d2 = wsum64(zai0 * zaq0 + zai1 * zaq1);
  float d3 = wsum64(zai0 * zq0 + zai1 * zq1);
  float d4 = wsum64(zi0 * zaq0 + zi1 * zaq1);
  if (lane == 0) {
    float ni = sqrtf(nzi), nai = sqrtf(nzai);
    float nq = sqrtf(nzq), naq = sqrtf(nzaq);
    float c1_ = d1 / fmaxf(ni * nq, 1e-8f) * TAU_INV;
    float ca1 = d2 / fmaxf(nai * naq, 1e-8f) * TAU_INV;
    float c2_ = d3 / fmaxf(nai * nq, 1e-8f) * TAU_INV;
    float ca2 = d4 / fmaxf(ni * naq, 1e-8f) * TAU_INV;
    simbuf[row] = make_float4(c1_, ca1, c2_, ca2);
    if (row == q) {
      scal_out[9] = c2_;
      scal_out[10] = ca2;
    }
  }
}

__global__ __launch_bounds__(256) void reduce_sim_k(const float4* __restrict__ simbuf,
                                                    const int* __restrict__ maskI,
                                                    float* __restrict__ scal) {
  float acc[9];
#pragma unroll
  for (int i = 0; i < 9; ++i) acc[i] = 0.f;
  for (int row = blockIdx.x * 256 + threadIdx.x; row < NN; row += gridDim.x * 256) {
    float4 v = simbuf[row];
    acc[0] += expf(v.x);
    acc[1] += expf(v.y);
    acc[2] += expf(v.z);
    acc[3] += expf(v.w);
    if (maskI[row]) {
      acc[4] += v.x; acc[5] += v.y; acc[6] += v.z; acc[7] += v.w;
      acc[8] += 1.0f;
    }
  }
  __shared__ float s[9][4];
  int lane = threadIdx.x & 63, wv = threadIdx.x >> 6;
#pragma unroll
  for (int i = 0; i < 9; ++i) {
    float r = wsum64(acc[i]);
    if (lane == 0) s[i][wv] = r;
  }
  __syncthreads();
  if (threadIdx.x < 9) {
    float r = s[threadIdx.x][0] + s[threadIdx.x][1] + s[threadIdx.x][2] + s[threadIdx.x][3];
    atomicAdd(&scal[threadIdx.x], r);
  }
}

__global__ void final_k(const float* __restrict__ scal, float* __restrict__ out) {
  if (threadIdx.x != 0 || blockIdx.x != 0) return;
  float S1 = scal[0], Sa1 = scal[1], S2 = scal[2], Sa2 = scal[3];
  float L1 = scal[4], La1 = scal[5], L2 = scal[6], La2 = scal[7];
  float NM = scal[8], Q2 = scal[9], Qa2 = scal[10];
  float intra = 0.5f * ((logf(S1) - L1 / NM) + (logf(Sa1) - La1 / NM));
  float inter = 0.5f * ((logf(S2) - L2 / NM) + (logf(Sa2) - La2 / NM));
  float unsup = 0.5f * (logf(S2) - Q2) + 0.5f * (logf(Sa2) - Qa2);
  out[0] = intra + 0.5f * inter + 0.5f * unsup;  // ALPHA=0.5, LAM=0.5
}

// ---------- host ----------
extern "C" void kernel_launch(void* const* d_in, const int* in_sizes, int n_in,
                              void* d_out, int out_size, void* d_ws, size_t ws_size,
                              hipStream_t stream) {
  const float* feats = (const float*)d_in[0];
  const int* ei = (const int*)d_in[1];
  const int* ea = (const int*)d_in[2];
  const int* pos = (const int*)d_in[3];
  const int* qp = (const int*)d_in[4];
  const float* Wq0 = (const float*)d_in[5];
  const float* bq0 = (const float*)d_in[6];
  const float* W0 = (const float*)d_in[7];
  const float* b0 = (const float*)d_in[8];
  const float* Whq0 = (const float*)d_in[9];
  const float* bhq0 = (const float*)d_in[10];
  const float* Wh0 = (const float*)d_in[11];
  const float* bh0 = (const float*)d_in[12];
  const float* Wf0 = (const float*)d_in[13];
  const float* bf0 = (const float*)d_in[14];
  const float* Wfh0 = (const float*)d_in[15];
  const float* bfh0 = (const float*)d_in[16];
  const float* aq0 = (const float*)d_in[17];
  const float* a0 = (const float*)d_in[18];
  const float* ahq0 = (const float*)d_in[19];
  const float* ah0 = (const float*)d_in[20];
  const float* aq_ = (const float*)d_in[21];
  const float* a_ = (const float*)d_in[22];
  const float* ahq_ = (const float*)d_in[23];
  const float* ah_ = (const float*)d_in[24];
  const float* Wlq = (const float*)d_in[25];
  const float* blq = (const float*)d_in[26];
  const float* Wlf = (const float*)d_in[27];
  const float* blf = (const float*)d_in[28];
  const float* Wm1 = (const float*)d_in[29];
  const float* bm1 = (const float*)d_in[30];
  const float* Wm2 = (const float*)d_in[31];
  const float* bm2 = (const float*)d_in[32];

  char* ws = (char*)d_ws;
  size_t off = 0;
  auto take = [&](size_t bytes) -> void* {
    void* p = ws + off;
    off = (off + bytes + 255) & ~(size_t)255;
    return p;
  };
  // ---- zero region ----
  int* cursor3 = (int*)take(3 * NN * 4);
  int* maskI = (int*)take(NN * 4);
  float* s_hq = (float*)take(NN * 4);
  float* cntq = (float*)take(NN * 4);
  float* s_hgq = (float*)take(NN * 4);
  float* scal = (float*)take(64 * 4);
  int* qcnt = (int*)take(24 * QPAD * 4);
  size_t zero_end = off;
  // ---- non-zeroed scratch ----
  unsigned short* slotsA = (unsigned short*)take((size_t)NN * CAP * 2);
  unsigned short* slotsB = (unsigned short*)take((size_t)NN * CAP * 2);
  unsigned short* slotsC = (unsigned short*)take((size_t)NN * CAP * 2);
  unsigned int* qdata = (unsigned int*)take((size_t)24 * QCAP * 4);
  float* dinv = (float*)take(NN * 4);
  float* Binv = (float*)take(NN * 4);
  float* Dninv = (float*)take(NN * 4);
  float4* simbuf = (float4*)take((size_t)NN * 16);
  unsigned short* Wpack = (unsigned short*)take((size_t)7 * 16384 * 2);
  const size_t BFSZ = (size_t)NN * HH * 2;
  unsigned short* B0 = (unsigned short*)take(BFSZ);
  unsigned short* B1 = (unsigned short*)take(BFSZ);
  unsigned short* B2 = (unsigned short*)take(BFSZ);
  unsigned short* B3 = (unsigned short*)take(BFSZ);
  unsigned short* B4 = (unsigned short*)take(BFSZ);
  unsigned short* B5 = (unsigned short*)take(BFSZ);
  unsigned short* B6 = (unsigned short*)take(BFSZ);  // feats2 bf16
  unsigned char* P1 = (unsigned char*)take((size_t)NN * 256);  // fp8 pair [node][2][128]
  unsigned char* P2 = (unsigned char*)take((size_t)NN * 256);
  unsigned char* P3 = (unsigned char*)take((size_t)NN * 256);

  const int EB = (EE + 255) / 256;
  const int GMB = (NN + 63) / 64;    // gemm blocks (64 rows each)
  const int GTB = (NN + 7) / 8;      // gather blocks (8 nodes/block, 32 lanes/node)
  const int RB = (NN + 3) / 4;       // row-wave blocks
  const short8* Wp = (const short8*)Wpack;

  hipMemsetAsync(d_ws, 0, zero_end, stream);
  pack_k<<<(7 * 2048 + 255) / 256, 256, 0, stream>>>(W0, Wh0, Wlf, Wf0, Wfh0, Wm1, Wm2,
                                                     Wpack);
  // radix fill: bin edges once into (role x partition) queues, then LDS-cursor fill
  bin_k<<<BINB, 256, 0, stream>>>(ei, ea, qcnt, qdata, pos, qp, maskI);
  fillp_k<<<24 * WSUB, 256, 0, stream>>>(qcnt, qdata, cursor3, slotsA, slotsB, slotsC,
                                         cntq, qp, dinv, Binv, Dninv);
  // feats @ {W0, Wh0, Wlf}: xw0 -> P1.half0 (fp8), xwh -> P2.half0 (fp8), feats2 -> B6 bf16
  gemm3_mfma<<<2 * GMB, 256, 0, stream>>>(feats, Wp, blf, P1, P2, B6, NN);
  // fused {shq | fuse2}: both ready after fillp+gemm3 (fuse2 -> B3=hf_, B4=hfh_)
  f2_k<<<EB + RB, 256, 0, stream>>>(ei, ea, qp, dinv, Binv, cntq, s_hq, s_hgq, B6, Wlq,
                                    blq, aq_, a_, ahq_, ah_, B3, B4, EB);
  // xwf -> P1.half1 ; xwfh -> P2.half1  (fp8, batched)
  gemm2_mfma<false, false, 2><<<2 * GMB, 256, 0, stream>>>(
      B3, B4, Wp + (size_t)3 * 2048, Wp + (size_t)4 * 2048, nullptr, nullptr, P1 + 128,
      P2 + 128, NN, GMB);
  // gathers: pass1 GCN P1 -> fused epilogue -> B3=hf ; pass2 HG-he P2 -> P3 fp8 [merged]
  // (B3 safe to overwrite: gemm2-fp8 above already consumed hf_)
  dgather12_k<<<2 * GTB, 256, 0, stream>>>((const uint2*)P1, B3, (const uint2*)P2,
                                           (uint2*)P3, cursor3, slotsA, slotsB, dinv, Binv,
                                           s_hq, Wq0, bq0, b0, aq0, a0, bf0, GTB);
  // pass3 HG-node P3 -> fused epilogue -> B4=h_augf
  dgather3_k<<<GTB, 256, 0, stream>>>((const uint2*)P3, B4, cursor3, slotsC, Dninv, s_hgq,
                                      Whq0, bhq0, bh0, ahq0, ah0, bfh0);
  // MLPs (batched per layer): L1: (B3->B0),(B4->B1) ; L2: (B0->B2=z),(B1->B5=z_aug) bf16
  gemm2_mfma<true, true, 1><<<2 * GMB, 256, 0, stream>>>(
      B3, B4, Wp + (size_t)5 * 2048, Wp + (size_t)5 * 2048, bm1, bm1, B0, B1, NN, GMB);
  gemm2_mfma<true, false, 1><<<2 * GMB, 256, 0, stream>>>(
      B0, B1, Wp + (size_t)6 * 2048, Wp + (size_t)6 * 2048, bm2, bm2, B2, B5, NN, GMB);
  // loss
  sim_k<<<RB, 256, 0, stream>>>(B2, B5, qp, simbuf, scal);
  reduce_sim_k<<<64, 256, 0, stream>>>(simbuf, maskI, scal);
  final_k<<<1, 64, 0, stream>>>(scal, (float*)d_out);
}

// Round 13
// 400.400 us; speedup vs baseline: 1.0740x; 1.0136x over previous
//
#include <hip/hip_runtime.h>

#define NN 50000
#define EE 600000
#define HH 128
#define TAU_INV 2.0f   // 1/TAU, TAU=0.5
#define PSZ 6250       // NN / 8 partitions (partition <-> XCD fixed bijection)
#define CAP 48         // bucket capacity; max degree for multinomial(600k,1/50k) ~ 36

// radix-fill parameters
#define BINB 512                         // bin_k blocks
#define BUFC 240                         // per-(role,part) LDS buffer cap per BLOCK
#define QCAP 80000                       // per-(role,part) queue cap (mean 75000, +19 sigma)
#define QPAD 16                          // qcnt stride (ints) -> one counter per 64B line
#define WSUB 32                          // sub-ranges per (role,partition)
#define SUBN 196                         // ceil(PSZ/WSUB)

typedef __attribute__((ext_vector_type(8))) short short8;
typedef __attribute__((ext_vector_type(4))) float f32x4;
typedef __attribute__((ext_vector_type(2))) float floatx2;

// ---------- helpers ----------
__device__ __forceinline__ float wsum64(float v) {
#pragma unroll
  for (int m = 32; m >= 1; m >>= 1) v += __shfl_xor(v, m, 64);
  return v;
}
__device__ __forceinline__ unsigned short f2bf(float f) {
  unsigned u = __builtin_bit_cast(unsigned, f);
  u = u + 0x7FFFu + ((u >> 16) & 1u);
  return (unsigned short)(u >> 16);
}
__device__ __forceinline__ float bf2f(unsigned short h) {
  unsigned u = ((unsigned)h) << 16;
  return __builtin_bit_cast(float, u);
}
// fp8 e4m3 (OCP) via gfx950 HW converts
__device__ __forceinline__ unsigned char fp8_enc1(float v) {
  int p = __builtin_amdgcn_cvt_pk_fp8_f32(v, v, 0, false);
  return (unsigned char)(p & 0xFF);
}
__device__ __forceinline__ void fp8x8_dec(uint2 v, float* f) {
  floatx2 a = __builtin_amdgcn_cvt_pk_f32_fp8(v.x, false);
  floatx2 b = __builtin_amdgcn_cvt_pk_f32_fp8(v.x, true);
  floatx2 c = __builtin_amdgcn_cvt_pk_f32_fp8(v.y, false);
  floatx2 d = __builtin_amdgcn_cvt_pk_f32_fp8(v.y, true);
  f[0] = a.x; f[1] = a.y; f[2] = b.x; f[3] = b.y;
  f[4] = c.x; f[5] = c.y; f[6] = d.x; f[7] = d.y;
}
__device__ __forceinline__ uint2 fp8x8_enc(const float* f) {
  int w0 = __builtin_amdgcn_cvt_pk_fp8_f32(f[0], f[1], 0, false);
  w0 = __builtin_amdgcn_cvt_pk_fp8_f32(f[2], f[3], w0, true);
  int w1 = __builtin_amdgcn_cvt_pk_fp8_f32(f[4], f[5], 0, false);
  w1 = __builtin_amdgcn_cvt_pk_fp8_f32(f[6], f[7], w1, true);
  return make_uint2((unsigned)w0, (unsigned)w1);
}

#define LDSW 136  // 128 + 8 bf16 pad

// ---------- phase 1: bin edges into (role x partition) queues ----------
// role 0: key=dst, pay=src (GCN)   role 1: key=he, pay=node   role 2: key=node, pay=he
__global__ __launch_bounds__(256) void bin_k(const int* __restrict__ ei,
                                             const int* __restrict__ ea,
                                             int* __restrict__ qcnt,
                                             unsigned int* __restrict__ qdata,
                                             const int* __restrict__ pos,
                                             const int* __restrict__ qp,
                                             int* __restrict__ maskI) {
  __shared__ int cnt[24], base[24], pfx[25];
  __shared__ unsigned int buf[24 * BUFC];
  const int tid = threadIdx.x;
  if (tid < 24) cnt[tid] = 0;
  if (blockIdx.x == 0 && tid < 100) maskI[pos[tid]] = 1;
  __syncthreads();
  if (blockIdx.x == 0 && tid == 0) maskI[*qp] = 0;
  for (int e = blockIdx.x * 256 + tid; e < EE; e += BINB * 256) {
    int pay0 = __builtin_nontemporal_load(ei + e);      // src
    int k0 = __builtin_nontemporal_load(ei + EE + e);   // dst
    int pay1 = __builtin_nontemporal_load(ea + e);      // node
    int k1 = __builtin_nontemporal_load(ea + EE + e);   // he
    int k2 = pay1, pay2 = k1;
    int g0 = k0 / PSZ;
    int g1 = 8 + k1 / PSZ;
    int g2 = 16 + k2 / PSZ;
    int o0 = atomicAdd(&cnt[g0], 1);
    int o1 = atomicAdd(&cnt[g1], 1);
    int o2 = atomicAdd(&cnt[g2], 1);
    if (o0 < BUFC) buf[g0 * BUFC + o0] = ((unsigned)k0 << 16) | (unsigned)pay0;
    if (o1 < BUFC) buf[g1 * BUFC + o1] = ((unsigned)k1 << 16) | (unsigned)pay1;
    if (o2 < BUFC) buf[g2 * BUFC + o2] = ((unsigned)k2 << 16) | (unsigned)pay2;
  }
  __syncthreads();
  if (tid < 24) {
    int c = min(cnt[tid], BUFC);
    cnt[tid] = c;
    base[tid] = atomicAdd(&qcnt[tid * QPAD], c);  // padded: 1 counter per 64B line
  }
  __syncthreads();
  if (tid == 0) {
    int s = 0;
#pragma unroll
    for (int g = 0; g < 24; ++g) { pfx[g] = s; s += cnt[g]; }
    pfx[24] = s;
  }
  __syncthreads();
  const int total = pfx[24];
  for (int j = tid; j < total; j += 256) {
    int lo2 = 0, hi2 = 24;
    while (lo2 + 1 < hi2) {
      int mid = (lo2 + hi2) >> 1;
      if (j >= pfx[mid]) lo2 = mid; else hi2 = mid;
    }
    int g = lo2;
    int i = j - pfx[g];
    int dq = base[g] + i;
    if (dq < QCAP) qdata[(size_t)g * QCAP + dq] = buf[g * BUFC + i];
  }
}

// ---------- phase 2: partitioned fill with LDS cursors (+ fused derive + s_hq count) -----
// Role 0 additionally counts q-sourced edges per dst (replaces the shq edge re-scan):
// s_hq[dst] = count(src==q) + [dst==q]; scaled by dinv[q]*dinv[dst] at consumption.
__global__ __launch_bounds__(256) void fillp_k(const int* __restrict__ qcnt,
                                               const unsigned int* __restrict__ qdata,
                                               int* __restrict__ cursor,
                                               unsigned short* __restrict__ slotsA,
                                               unsigned short* __restrict__ slotsB,
                                               unsigned short* __restrict__ slotsC,
                                               float* __restrict__ cntq,
                                               const int* __restrict__ qp,
                                               float* __restrict__ dinv,
                                               float* __restrict__ Binv,
                                               float* __restrict__ Dninv,
                                               float* __restrict__ s_hq) {
  __shared__ int cur[SUBN];
  __shared__ int qcur[SUBN];
  const int w = blockIdx.x;  // 0..767
  const int p = w & 7;
  const int r = (w >> 3) % 3;
  const int s = w / 24;
  const int lo = p * PSZ + s * SUBN;
  const int hi = min(lo + SUBN, (p + 1) * PSZ);
  const int tid = threadIdx.x;
  if (tid < SUBN) { cur[tid] = 0; qcur[tid] = 0; }
  __syncthreads();
  const int g = r * 8 + p;
  const int qlen = min(qcnt[g * QPAD], QCAP);
  const unsigned int* qd = qdata + (size_t)g * QCAP;
  unsigned short* slots = (r == 0) ? slotsA : (r == 1) ? slotsB : slotsC;
  const int q = *qp;
  auto proc = [&](unsigned int rec) {
    int key = (int)(rec >> 16);
    if (key >= lo && key < hi) {
      int pay = (int)(rec & 0xFFFFu);
      int idx = atomicAdd(&cur[key - lo], 1);
      if (idx < CAP) slots[key * CAP + idx] = (unsigned short)pay;
      if (r == 0 && pay == q) atomicAdd(&qcur[key - lo], 1);
      if (r == 1 && pay == q) atomicAdd(&cntq[key], 1.0f);
    }
  };
  const int nv4 = qlen >> 2;
  const uint4* qd4 = (const uint4*)qd;
  int j = tid;
  for (; j + 256 < nv4; j += 512) {
    uint4 r0 = qd4[j];
    uint4 r1 = qd4[j + 256];
    proc(r0.x); proc(r0.y); proc(r0.z); proc(r0.w);
    proc(r1.x); proc(r1.y); proc(r1.z); proc(r1.w);
  }
  if (j < nv4) {
    uint4 r0 = qd4[j];
    proc(r0.x); proc(r0.y); proc(r0.z); proc(r0.w);
  }
  int i = (nv4 << 2) + tid;
  if (i < qlen) proc(qd[i]);
  __syncthreads();
  for (int k = lo + tid; k < hi; k += 256) {
    int c = cur[k - lo];
    cursor[r * NN + k] = c;
    if (r == 0) {
      dinv[k] = rsqrtf((float)(c + 1));  // deg incl. self-loop
      s_hq[k] = (float)(qcur[k - lo] + (k == q ? 1 : 0));
    } else if (r == 1) Binv[k] = (c > 0) ? 1.0f / (float)c : 0.0f;
    else Dninv[k] = (c > 0) ? 1.0f / (float)c : 0.0f;
  }
}

// ---------- fuse2: hf_ and hfh_ from analytic querys2 and feats2(bf16) ----------
__global__ void fuse2_k(const unsigned short* __restrict__ f2, const int* __restrict__ qp,
                        const float* __restrict__ Wlq, const float* __restrict__ blq,
                        const float* __restrict__ aq1, const float* __restrict__ a1,
                        const float* __restrict__ aq2, const float* __restrict__ a2,
                        unsigned short* __restrict__ out1, unsigned short* __restrict__ out2) {
  int row = blockIdx.x * 4 + (threadIdx.x >> 6);
  if (row >= NN) return;
  int lane = threadIdx.x & 63;
  int c0 = lane, c1 = lane + 64;
  int q = *qp;
  float q20 = blq[c0] + ((row == q) ? Wlq[c0] : 0.f);
  float q21 = blq[c1] + ((row == q) ? Wlq[c1] : 0.f);
  float f0 = bf2f(f2[(size_t)row * 128 + c0]);
  float f1 = bf2f(f2[(size_t)row * 128 + c1]);
  float dq1 = wsum64(q20 * aq1[c0] + q21 * aq1[c1]);
  float df1 = wsum64(f0 * a1[c0] + f1 * a1[c1]);
  float dq2 = wsum64(q20 * aq2[c0] + q21 * aq2[c1]);
  float df2 = wsum64(f0 * a2[c0] + f1 * a2[c1]);
  {
    float mx = fmaxf(dq1, df1);
    float e0 = expf(dq1 - mx), e1 = expf(df1 - mx);
    float w0 = e0 / (e0 + e1), w1 = 1.f - w0;
    out1[(size_t)row * 128 + c0] = f2bf(w0 * q20 + w1 * f0);
    out1[(size_t)row * 128 + c1] = f2bf(w0 * q21 + w1 * f1);
  }
  {
    float mx = fmaxf(dq2, df2);
    float e0 = expf(dq2 - mx), e1 = expf(df2 - mx);
    float w0 = e0 / (e0 + e1), w1 = 1.f - w0;
    out2[(size_t)row * 128 + c0] = f2bf(w0 * q20 + w1 * f0);
    out2[(size_t)row * 128 + c1] = f2bf(w0 * q21 + w1 * f1);
  }
}

// ---------- pack 7 weight matrices into MFMA B-fragment order ----------
__global__ void pack_k(const float* __restrict__ W0, const float* __restrict__ Wh0,
                       const float* __restrict__ Wlf, const float* __restrict__ Wf0,
                       const float* __restrict__ Wfh0, const float* __restrict__ Wm1,
                       const float* __restrict__ Wm2, unsigned short* __restrict__ out) {
  int tid = blockIdx.x * 256 + threadIdx.x;
  if (tid >= 7 * 2048) return;
  int mat = tid >> 11, r = tid & 2047;
  int s = r >> 9, c = (r >> 6) & 7, lane = r & 63;
  const float* W = (mat == 0) ? W0 : (mat == 1) ? Wh0 : (mat == 2) ? Wlf
                 : (mat == 3) ? Wf0 : (mat == 4) ? Wfh0 : (mat == 5) ? Wm1 : Wm2;
  int k0 = 32 * s + (lane >> 4) * 8;
  int n = 16 * c + (lane & 15);
  unsigned short* o = out + (size_t)tid * 8;
#pragma unroll
  for (int j = 0; j < 8; ++j) o[j] = f2bf(W[(k0 + j) * 128 + n]);
}

// ---------- gemm core (A staged in LDS as bf16; LDS-staged coalesced epilogue) ----------
// OM: 1 = bf16 out (ushort stride 128), 2 = fp8 out (uchar stride 256).
template <bool BIAS, bool RELU, int OM>
__device__ __forceinline__ void gemm_core(unsigned short* As, const short8* Wp,
                                          const float* bias, void* outv, int r0, int nrows,
                                          int tid) {
  const int wave = tid >> 6, lane = tid & 63;
  const int quad = lane >> 4, l15 = lane & 15;
  f32x4 acc[8];
#pragma unroll
  for (int c = 0; c < 8; ++c) acc[c] = (f32x4){0.f, 0.f, 0.f, 0.f};
#pragma unroll
  for (int s = 0; s < 4; ++s) {
    short8 a = *(const short8*)&As[(wave * 16 + l15) * LDSW + s * 32 + quad * 8];
#pragma unroll
    for (int c = 0; c < 8; ++c) {
      short8 b = Wp[(s * 8 + c) * 64 + lane];
      acc[c] = __builtin_amdgcn_mfma_f32_16x16x32_bf16(a, b, acc[c], 0, 0, 0);
    }
  }
  __syncthreads();  // all waves done reading As before overwrite
  const int rwl = wave * 16 + quad * 4;  // local row base
  if (OM == 2) {
    unsigned char* l8 = (unsigned char*)As;  // [64][128] fp8 = 8KB
#pragma unroll
    for (int c = 0; c < 8; ++c) {
      int col = c * 16 + l15;
      float bv = BIAS ? bias[col] : 0.f;
#pragma unroll
      for (int r = 0; r < 4; ++r) {
        float v = acc[c][r] + bv;
        if (RELU) v = fmaxf(v, 0.f);
        l8[(rwl + r) * 128 + col] = fp8_enc1(v);
      }
    }
    __syncthreads();
#pragma unroll
    for (int t = 0; t < 2; ++t) {
      int idx = (t * 256 + tid) * 16;  // 0..8191
      int row = idx >> 7, off = idx & 127;
      int grow = r0 + row;
      if (grow < nrows)
        *(uint4*)&((unsigned char*)outv)[(size_t)grow * 256 + off] = *(uint4*)&l8[idx];
    }
  } else {
    unsigned short* l16 = As;  // [64][128] ushort = 16KB
#pragma unroll
    for (int c = 0; c < 8; ++c) {
      int col = c * 16 + l15;
      float bv = BIAS ? bias[col] : 0.f;
#pragma unroll
      for (int r = 0; r < 4; ++r) {
        float v = acc[c][r] + bv;
        if (RELU) v = fmaxf(v, 0.f);
        l16[(rwl + r) * 128 + col] = f2bf(v);
      }
    }
    __syncthreads();
#pragma unroll
    for (int t = 0; t < 4; ++t) {
      int idx = (t * 256 + tid) * 16;  // byte idx 0..16383
      int row = idx >> 8, off = idx & 255;
      int grow = r0 + row;
      if (grow < nrows)
        *(uint4*)&((unsigned char*)outv)[(size_t)grow * 256 + off] =
            *(uint4*)&((unsigned char*)l16)[idx];
    }
  }
}

__device__ __forceinline__ void stage_bf16(const unsigned short* A, unsigned short* As,
                                           int r0, int nrows, int tid) {
#pragma unroll
  for (int t = 0; t < 4; ++t) {
    int v = t * 256 + tid;
    int row = v >> 4, cc = v & 15;
    int gr = r0 + row;
    uint4 val = make_uint4(0, 0, 0, 0);
    if (gr < nrows) val = ((const uint4*)A)[(size_t)gr * 16 + cc];
    *(uint4*)&As[row * LDSW + cc * 8] = val;
  }
}

// ---------- batched pair GEMM: two independent A@W ----------
template <bool BIAS, bool RELU, int OM>
__global__ __launch_bounds__(256) void gemm2_mfma(const unsigned short* __restrict__ A0,
                                                  const unsigned short* __restrict__ A1,
                                                  const short8* __restrict__ Wp0,
                                                  const short8* __restrict__ Wp1,
                                                  const float* __restrict__ b0,
                                                  const float* __restrict__ b1,
                                                  void* __restrict__ o0, void* __restrict__ o1,
                                                  int nrows, int nblk) {
  __shared__ unsigned short As[64 * LDSW];
  int b = blockIdx.x;
  const unsigned short* A = A0;
  const short8* Wp = Wp0;
  const float* bias = b0;
  void* o = o0;
  if (b >= nblk) {
    b -= nblk; A = A1; Wp = Wp1; bias = b1; o = o1;
  }
  const int r0 = b * 64;
  stage_bf16(A, As, r0, nrows, threadIdx.x);
  __syncthreads();
  gemm_core<BIAS, RELU, OM>(As, Wp, bias, o, r0, nrows, threadIdx.x);
}

// ---------- fused 2-layer MLP: out = relu(A@Wm1+bm1)@Wm2+bm2, batched pair ----------
// Layer-2 contraction is row-local, so chain both layers per 64-row block via LDS:
// eliminates the 51MB B0/B1 round-trip + one launch.
__global__ __launch_bounds__(256) void gemm22_mfma(const unsigned short* __restrict__ A0,
                                                   const unsigned short* __restrict__ A1,
                                                   const short8* __restrict__ Wp1,
                                                   const short8* __restrict__ Wp2,
                                                   const float* __restrict__ bm1,
                                                   const float* __restrict__ bm2,
                                                   unsigned short* __restrict__ o0,
                                                   unsigned short* __restrict__ o1,
                                                   int nrows, int nblk) {
  __shared__ unsigned short As[64 * LDSW];
  __shared__ unsigned short Bs[64 * LDSW];
  int b = blockIdx.x;
  const unsigned short* A = A0;
  unsigned short* o = o0;
  if (b >= nblk) { b -= nblk; A = A1; o = o1; }
  const int r0 = b * 64;
  const int tid = threadIdx.x;
  stage_bf16(A, As, r0, nrows, tid);
  __syncthreads();
  const int wave = tid >> 6, lane = tid & 63;
  const int quad = lane >> 4, l15 = lane & 15;
  const int rwl = wave * 16 + quad * 4;
  f32x4 acc[8];
  // layer 1
#pragma unroll
  for (int c = 0; c < 8; ++c) acc[c] = (f32x4){0.f, 0.f, 0.f, 0.f};
#pragma unroll
  for (int s = 0; s < 4; ++s) {
    short8 a = *(const short8*)&As[(wave * 16 + l15) * LDSW + s * 32 + quad * 8];
#pragma unroll
    for (int c = 0; c < 8; ++c)
      acc[c] = __builtin_amdgcn_mfma_f32_16x16x32_bf16(a, Wp1[(s * 8 + c) * 64 + lane],
                                                       acc[c], 0, 0, 0);
  }
  // relu+bias -> Bs in A-layout (contraction index = column)
#pragma unroll
  for (int c = 0; c < 8; ++c) {
    int col = c * 16 + l15;
    float bv = bm1[col];
#pragma unroll
    for (int r = 0; r < 4; ++r)
      Bs[(rwl + r) * LDSW + col] = f2bf(fmaxf(acc[c][r] + bv, 0.f));
  }
  __syncthreads();  // Bs ready; all As reads done
  // layer 2
#pragma unroll
  for (int c = 0; c < 8; ++c) acc[c] = (f32x4){0.f, 0.f, 0.f, 0.f};
#pragma unroll
  for (int s = 0; s < 4; ++s) {
    short8 a = *(const short8*)&Bs[(wave * 16 + l15) * LDSW + s * 32 + quad * 8];
#pragma unroll
    for (int c = 0; c < 8; ++c)
      acc[c] = __builtin_amdgcn_mfma_f32_16x16x32_bf16(a, Wp2[(s * 8 + c) * 64 + lane],
                                                       acc[c], 0, 0, 0);
  }
  // epilogue: stage into As (free), coalesced copy-out
  unsigned short* l16 = As;
#pragma unroll
  for (int c = 0; c < 8; ++c) {
    int col = c * 16 + l15;
    float bv = bm2[col];
#pragma unroll
    for (int r = 0; r < 4; ++r) l16[(rwl + r) * 128 + col] = f2bf(acc[c][r] + bv);
  }
  __syncthreads();
#pragma unroll
  for (int t = 0; t < 4; ++t) {
    int idx = (t * 256 + tid) * 16;
    int row = idx >> 8, off = idx & 255;
    int grow = r0 + row;
    if (grow < nrows)
      *(uint4*)&((unsigned char*)o)[(size_t)grow * 256 + off] =
          *(uint4*)&((unsigned char*)l16)[idx];
  }
}

// ---------- 3 GEMMs sharing one fp32-A tile; column-halved for occupancy ----------
__global__ __launch_bounds__(256) void gemm3_mfma(const float* __restrict__ A,
                                                  const short8* __restrict__ Wp,  // mats 0,1,2
                                                  const float* __restrict__ bias2,
                                                  unsigned char* __restrict__ p1,
                                                  unsigned char* __restrict__ p2,
                                                  unsigned short* __restrict__ out2,
                                                  int nrows) {
  __shared__ unsigned short As[64 * LDSW];
  const int tid = threadIdx.x;
  const int bh = blockIdx.x & 1;
  const int r0 = (blockIdx.x >> 1) * 64;
#pragma unroll
  for (int t = 0; t < 8; ++t) {
    int v = t * 256 + tid;
    int row = v >> 5, c4 = v & 31;  // float4 chunk
    int gr = r0 + row;
    f32x4 val = (f32x4){0.f, 0.f, 0.f, 0.f};
    if (gr < nrows) val = ((const f32x4*)A)[(size_t)gr * 32 + c4];  // plain: L3 reuse
    ushort4 o;
    o.x = f2bf(val.x); o.y = f2bf(val.y); o.z = f2bf(val.z); o.w = f2bf(val.w);
    *(ushort4*)&As[row * LDSW + c4 * 4] = o;
  }
  __syncthreads();
  const int wave = tid >> 6, lane = tid & 63;
  const int quad = lane >> 4, l15 = lane & 15;
  f32x4 acc[3][4];
#pragma unroll
  for (int m = 0; m < 3; ++m)
#pragma unroll
    for (int c = 0; c < 4; ++c) acc[m][c] = (f32x4){0.f, 0.f, 0.f, 0.f};
#pragma unroll
  for (int s = 0; s < 4; ++s) {
    short8 a = *(const short8*)&As[(wave * 16 + l15) * LDSW + s * 32 + quad * 8];
#pragma unroll
    for (int m = 0; m < 3; ++m)
#pragma unroll
      for (int c = 0; c < 4; ++c) {
        short8 bb = Wp[(size_t)m * 2048 + (s * 8 + bh * 4 + c) * 64 + lane];
        acc[m][c] = __builtin_amdgcn_mfma_f32_16x16x32_bf16(a, bb, acc[m][c], 0, 0, 0);
      }
  }
  __syncthreads();  // done reading As
  // stage outputs: P1 [64][64]B @0, P2 @4096, B6 [64][64]ushort @8192 (16KB total)
  unsigned char* l8a = (unsigned char*)As;
  unsigned char* l8b = l8a + 4096;
  unsigned short* l16 = (unsigned short*)(l8a + 8192);
  const int rwl = wave * 16 + quad * 4;
#pragma unroll
  for (int c = 0; c < 4; ++c) {
    int coll = c * 16 + l15;                 // local col 0..63
    float bv = bias2[(bh * 4 + c) * 16 + l15];
#pragma unroll
    for (int r = 0; r < 4; ++r) {
      int lrow = rwl + r;
      l8a[lrow * 64 + coll] = fp8_enc1(acc[0][c][r]);
      l8b[lrow * 64 + coll] = fp8_enc1(acc[1][c][r]);
      l16[lrow * 64 + coll] = f2bf(acc[2][c][r] + bv);
    }
  }
  __syncthreads();
  {  // P1/P2: 4KB each, 16B per thread, rows are 64B-contiguous chunks
    int idx = tid * 16;
    int row = idx >> 6, off = idx & 63;
    int grow = r0 + row;
    if (grow < nrows) {
      *(uint4*)&p1[(size_t)grow * 256 + bh * 64 + off] = *(uint4*)&l8a[idx];
      *(uint4*)&p2[(size_t)grow * 256 + bh * 64 + off] = *(uint4*)&l8b[idx];
    }
  }
#pragma unroll
  for (int t = 0; t < 2; ++t) {  // B6: 8KB, rows are 128B-contiguous chunks
    int idx = (t * 256 + tid) * 16;
    int row = idx >> 7, off = idx & 127;
    int grow = r0 + row;
    if (grow < nrows)
      *(uint4*)&((unsigned char*)out2)[(size_t)grow * 256 + bh * 128 + off] =
          *(uint4*)&((unsigned char*)l16)[idx];
  }
}

// ---------- paired gather (bucket CSR), fp8-pair input, 4x-unrolled (R8 structure) ------
// OUT 0: fp8-pair out (yp).  OUT 2: FUSED fuse_add epilogue -> bf16 out (outf).
// SQ: inline s_hgq = sum Binv[he]*cntq[he] over slots (replaces the shq edge re-scan).
// MODE 0 epilogue coeff: s = s_hqcnt[node]*dinv[q]*dinv[node].
template <int MODE, int OUT, bool SQ>
__device__ __forceinline__ void gpair_body(const uint2* __restrict__ xp,
                                           uint2* __restrict__ yp,
                                           unsigned short* __restrict__ outf,
                                           const int* __restrict__ cnt,
                                           const unsigned short* __restrict__ slots,
                                           const float* __restrict__ wv,
                                           const float* __restrict__ svec,
                                           const float* __restrict__ BinvT,
                                           const float* __restrict__ cntqT,
                                           const int* __restrict__ qp,
                                           const float* __restrict__ Wq,
                                           const float* __restrict__ bq,
                                           const float* __restrict__ bm,
                                           const float* __restrict__ aq,
                                           const float* __restrict__ am,
                                           const float* __restrict__ bres, int blk) {
  int node = blk * 8 + (threadIdx.x >> 5);
  if (node >= NN) return;
  int l = threadIdx.x & 31;
  int st = node * CAP;
  int n = min(cnt[node], CAP);
  float acc[8];
#pragma unroll
  for (int i = 0; i < 8; ++i) acc[i] = 0.f;
  float sq = 0.f;
  int p = 0;
  for (; p + 4 <= n; p += 4) {
    ushort4 s4 = *(const ushort4*)&slots[st + p];
    uint2 v0 = xp[(size_t)s4.x * 32 + l];
    uint2 v1 = xp[(size_t)s4.y * 32 + l];
    uint2 v2 = xp[(size_t)s4.z * 32 + l];
    uint2 v3 = xp[(size_t)s4.w * 32 + l];
    if (SQ) {
      sq += BinvT[s4.x] * cntqT[s4.x] + BinvT[s4.y] * cntqT[s4.y] +
            BinvT[s4.z] * cntqT[s4.z] + BinvT[s4.w] * cntqT[s4.w];
    }
    float f[8];
    if (MODE == 0) {
      float w0 = wv[s4.x], w1 = wv[s4.y], w2 = wv[s4.z], w3 = wv[s4.w];
      fp8x8_dec(v0, f);
#pragma unroll
      for (int i = 0; i < 8; ++i) acc[i] = fmaf(w0, f[i], acc[i]);
      fp8x8_dec(v1, f);
#pragma unroll
      for (int i = 0; i < 8; ++i) acc[i] = fmaf(w1, f[i], acc[i]);
      fp8x8_dec(v2, f);
#pragma unroll
      for (int i = 0; i < 8; ++i) acc[i] = fmaf(w2, f[i], acc[i]);
      fp8x8_dec(v3, f);
#pragma unroll
      for (int i = 0; i < 8; ++i) acc[i] = fmaf(w3, f[i], acc[i]);
    } else {
      fp8x8_dec(v0, f);
#pragma unroll
      for (int i = 0; i < 8; ++i) acc[i] += f[i];
      fp8x8_dec(v1, f);
#pragma unroll
      for (int i = 0; i < 8; ++i) acc[i] += f[i];
      fp8x8_dec(v2, f);
#pragma unroll
      for (int i = 0; i < 8; ++i) acc[i] += f[i];
      fp8x8_dec(v3, f);
#pragma unroll
      for (int i = 0; i < 8; ++i) acc[i] += f[i];
    }
  }
  for (; p < n; ++p) {
    int s = slots[st + p];
    uint2 v = xp[(size_t)s * 32 + l];
    if (SQ) sq += BinvT[s] * cntqT[s];
    float f[8];
    fp8x8_dec(v, f);
    if (MODE == 0) {
      float w = wv[s];
#pragma unroll
      for (int i = 0; i < 8; ++i) acc[i] = fmaf(w, f[i], acc[i]);
    } else {
#pragma unroll
      for (int i = 0; i < 8; ++i) acc[i] += f[i];
    }
  }
  float sc = wv[node];
  if (MODE == 0) {
    uint2 v = xp[(size_t)node * 32 + l];
    float f[8];
    fp8x8_dec(v, f);
#pragma unroll
    for (int i = 0; i < 8; ++i) acc[i] = sc * fmaf(sc, f[i], acc[i]);
  } else {
#pragma unroll
    for (int i = 0; i < 8; ++i) acc[i] *= sc;
  }
  if (OUT == 0) {
    yp[(size_t)node * 32 + l] = fp8x8_enc(acc);
  } else {
    // ---- fused fuse_add epilogue ----
    float y2v[8];
#pragma unroll
    for (int i = 0; i < 8; ++i) y2v[i] = __shfl_xor(acc[i], 16, 64);
    float s;
    if (MODE == 0) s = svec[node] * wv[*qp] * sc;  // count * dinv[q] * dinv[node]
    else s = sq * sc;                              // inline s_hgq * Dninv[node]
    int cg = l & 15;
    float h[8], hq[8];
    float pdm = 0.f, pdq = 0.f;
#pragma unroll
    for (int i = 0; i < 8; ++i) {
      int c = cg * 8 + i;
      h[i] = fmaxf(acc[i] + bm[c], 0.f);
      hq[i] = fmaxf(fmaf(s, Wq[c], bq[c]), 0.f);
      pdm = fmaf(h[i], am[c], pdm);
      pdq = fmaf(hq[i], aq[c], pdq);
    }
#pragma unroll
    for (int m = 1; m <= 8; m <<= 1) {  // reduce within 16-lane subgroup
      pdm += __shfl_xor(pdm, m, 64);
      pdq += __shfl_xor(pdq, m, 64);
    }
    float mx = fmaxf(pdq, pdm);
    float e0 = expf(pdq - mx), e1 = expf(pdm - mx);
    float w0 = e0 / (e0 + e1), w1 = 1.f - w0;
    if (l < 16) {  // lanes 16-31 hold y2-based partials; masked out
      unsigned short r[8];
#pragma unroll
      for (int i = 0; i < 8; ++i) {
        int c = cg * 8 + i;
        r[i] = f2bf(fmaxf(fmaf(w0, hq[i], fmaf(w1, h[i], y2v[i] + bres[c])), 0.f));
      }
      uint4 o;
      o.x = ((unsigned)r[1] << 16) | r[0];
      o.y = ((unsigned)r[3] << 16) | r[2];
      o.z = ((unsigned)r[5] << 16) | r[4];
      o.w = ((unsigned)r[7] << 16) | r[6];
      *(uint4*)&outf[(size_t)node * 128 + cg * 8] = o;
    }
  }
}

// merged: pass1 (GCN + fused epilogue -> B3) + pass2 (HG-he, fp8-pair out -> P3)
__global__ void dgather12_k(const uint2* __restrict__ xp1, unsigned short* __restrict__ B3,
                            const uint2* __restrict__ xp2, uint2* __restrict__ yp3,
                            const int* __restrict__ cursor,
                            const unsigned short* __restrict__ slotsA,
                            const unsigned short* __restrict__ slotsB,
                            const float* __restrict__ dinv, const float* __restrict__ Binv,
                            const float* __restrict__ s_hq, const int* __restrict__ qp,
                            const float* __restrict__ Wq0, const float* __restrict__ bq0,
                            const float* __restrict__ b0, const float* __restrict__ aq0,
                            const float* __restrict__ a0, const float* __restrict__ bf0,
                            int nblk) {
  int b = blockIdx.x;
  if (b < nblk)
    gpair_body<0, 2, false>(xp1, nullptr, B3, cursor, slotsA, dinv, s_hq, nullptr, nullptr,
                            qp, Wq0, bq0, b0, aq0, a0, bf0, b);
  else
    gpair_body<1, 0, false>(xp2, yp3, nullptr, cursor + NN, slotsB, Binv, nullptr, nullptr,
                            nullptr, nullptr, nullptr, nullptr, nullptr, nullptr, nullptr,
                            nullptr, b - nblk);
}

// pass3: HG-node gather + fused epilogue (inline s_hgq) -> B4
__global__ void dgather3_k(const uint2* __restrict__ xp, unsigned short* __restrict__ B4,
                           const int* __restrict__ cursor,
                           const unsigned short* __restrict__ slotsC,
                           const float* __restrict__ Dninv, const float* __restrict__ Binv,
                           const float* __restrict__ cntq,
                           const float* __restrict__ Whq0, const float* __restrict__ bhq0,
                           const float* __restrict__ bh0, const float* __restrict__ ahq0,
                           const float* __restrict__ ah0, const float* __restrict__ bfh0) {
  gpair_body<1, 2, true>(xp, nullptr, B4, cursor + 2 * NN, slotsC, Dninv, nullptr, Binv,
                         cntq, nullptr, Whq0, bhq0, bh0, ahq0, ah0, bfh0, blockIdx.x);
}

// ---------- per-row cosine logits (bf16 z, q-norms computed locally) ----------
__global__ void sim_k(const unsigned short* __restrict__ z,
                      const unsigned short* __restrict__ za, const int* __restrict__ qp,
                      float4* __restrict__ simbuf, float* __restrict__ scal_out) {
  int row = blockIdx.x * 4 + (threadIdx.x >> 6);
  if (row >= NN) return;
  int lane = threadIdx.x & 63;
  int c0 = lane, c1 = lane + 64;
  int q = *qp;
  float zi0 = bf2f(z[(size_t)row * 128 + c0]), zi1 = bf2f(z[(size_t)row * 128 + c1]);
  float zai0 = bf2f(za[(size_t)row * 128 + c0]), zai1 = bf2f(za[(size_t)row * 128 + c1]);
  float zq0 = bf2f(z[(size_t)q * 128 + c0]), zq1 = bf2f(z[(size_t)q * 128 + c1]);
  float zaq0 = bf2f(za[(size_t)q * 128 + c0]), zaq1 = bf2f(za[(size_t)q * 128 + c1]);
  float nzi = wsum64(zi0 * zi0 + zi1 * zi1);
  float nzai = wsum64(zai0 * zai0 + zai1 * zai1);
  float nzq = wsum64(zq0 * zq0 + zq1 * zq1);
  float nzaq = wsum64(zaq0 * zaq0 + zaq1 * zaq1);
  float d1 = wsum64(zi0 * zq0 + zi1 * zq1);
  float d2 = wsum64(zai0 * zaq0 + zai1 * zaq1);
  float d3 = wsum64(zai0 * zq0 + zai1 * zq1);
  float d4 = wsum64(zi0 * zaq0 + zi1 * zaq1);
  if (lane == 0) {
    float ni = sqrtf(nzi), nai = sqrtf(nzai);
    float nq = sqrtf(nzq), naq = sqrtf(nzaq);
    float c1_ = d1 / fmaxf(ni * nq, 1e-8f) * TAU_INV;
    float ca1 = d2 / fmaxf(nai * naq, 1e-8f) * TAU_INV;
    float c2_ = d3 / fmaxf(nai * nq, 1e-8f) * TAU_INV;
    float ca2 = d4 / fmaxf(ni * naq, 1e-8f) * TAU_INV;
    simbuf[row] = make_float4(c1_, ca1, c2_, ca2);
    if (row == q) {
      scal_out[9] = c2_;
      scal_out[10] = ca2;
    }
  }
}

__global__ __launch_bounds__(256) void reduce_sim_k(const float4* __restrict__ simbuf,
                                                    const int* __restrict__ maskI,
                                                    float* __restrict__ scal) {
  float acc[9];
#pragma unroll
  for (int i = 0; i < 9; ++i) acc[i] = 0.f;
  for (int row = blockIdx.x * 256 + threadIdx.x; row < NN; row += gridDim.x * 256) {
    float4 v = simbuf[row];
    acc[0] += expf(v.x);
    acc[1] += expf(v.y);
    acc[2] += expf(v.z);
    acc[3] += expf(v.w);
    if (maskI[row]) {
      acc[4] += v.x; acc[5] += v.y; acc[6] += v.z; acc[7] += v.w;
      acc[8] += 1.0f;
    }
  }
  __shared__ float s[9][4];
  int lane = threadIdx.x & 63, wv = threadIdx.x >> 6;
#pragma unroll
  for (int i = 0; i < 9; ++i) {
    float r = wsum64(acc[i]);
    if (lane == 0) s[i][wv] = r;
  }
  __syncthreads();
  if (threadIdx.x < 9) {
    float r = s[threadIdx.x][0] + s[threadIdx.x][1] + s[threadIdx.x][2] + s[threadIdx.x][3];
    atomicAdd(&scal[threadIdx.x], r);
  }
}

__global__ void final_k(const float* __restrict__ scal, float* __restrict__ out) {
  if (threadIdx.x != 0 || blockIdx.x != 0) return;
  float S1 = scal[0], Sa1 = scal[1], S2 = scal[2], Sa2 = scal[3];
  float L1 = scal[4], La1 = scal[5], L2 = scal[6], La2 = scal[7];
  float NM = scal[8], Q2 = scal[9], Qa2 = scal[10];
  float intra = 0.5f * ((logf(S1) - L1 / NM) + (logf(Sa1) - La1 / NM));
  float inter = 0.5f * ((logf(S2) - L2 / NM) + (logf(Sa2) - La2 / NM));
  float unsup = 0.5f * (logf(S2) - Q2) + 0.5f * (logf(Sa2) - Qa2);
  out[0] = intra + 0.5f * inter + 0.5f * unsup;  // ALPHA=0.5, LAM=0.5
}

// ---------- host ----------
extern "C" void kernel_launch(void* const* d_in, const int* in_sizes, int n_in,
                              void* d_out, int out_size, void* d_ws, size_t ws_size,
                              hipStream_t stream) {
  const float* feats = (const float*)d_in[0];
  const int* ei = (const int*)d_in[1];
  const int* ea = (const int*)d_in[2];
  const int* pos = (const int*)d_in[3];
  const int* qp = (const int*)d_in[4];
  const float* Wq0 = (const float*)d_in[5];
  const float* bq0 = (const float*)d_in[6];
  const float* W0 = (const float*)d_in[7];
  const float* b0 = (const float*)d_in[8];
  const float* Whq0 = (const float*)d_in[9];
  const float* bhq0 = (const float*)d_in[10];
  const float* Wh0 = (const float*)d_in[11];
  const float* bh0 = (const float*)d_in[12];
  const float* Wf0 = (const float*)d_in[13];
  const float* bf0 = (const float*)d_in[14];
  const float* Wfh0 = (const float*)d_in[15];
  const float* bfh0 = (const float*)d_in[16];
  const float* aq0 = (const float*)d_in[17];
  const float* a0 = (const float*)d_in[18];
  const float* ahq0 = (const float*)d_in[19];
  const float* ah0 = (const float*)d_in[20];
  const float* aq_ = (const float*)d_in[21];
  const float* a_ = (const float*)d_in[22];
  const float* ahq_ = (const float*)d_in[23];
  const float* ah_ = (const float*)d_in[24];
  const float* Wlq = (const float*)d_in[25];
  const float* blq = (const float*)d_in[26];
  const float* Wlf = (const float*)d_in[27];
  const float* blf = (const float*)d_in[28];
  const float* Wm1 = (const float*)d_in[29];
  const float* bm1 = (const float*)d_in[30];
  const float* Wm2 = (const float*)d_in[31];
  const float* bm2 = (const float*)d_in[32];

  char* ws = (char*)d_ws;
  size_t off = 0;
  auto take = [&](size_t bytes) -> void* {
    void* p = ws + off;
    off = (off + bytes + 255) & ~(size_t)255;
    return p;
  };
  // ---- zero region ----
  int* cursor3 = (int*)take(3 * NN * 4);
  int* maskI = (int*)take(NN * 4);
  float* s_hq = (float*)take(NN * 4);
  float* cntq = (float*)take(NN * 4);
  float* s_hgq = (float*)take(NN * 4);  // unused (kept for layout stability)
  float* scal = (float*)take(64 * 4);
  int* qcnt = (int*)take(24 * QPAD * 4);
  size_t zero_end = off;
  // ---- non-zeroed scratch ----
  unsigned short* slotsA = (unsigned short*)take((size_t)NN * CAP * 2);
  unsigned short* slotsB = (unsigned short*)take((size_t)NN * CAP * 2);
  unsigned short* slotsC = (unsigned short*)take((size_t)NN * CAP * 2);
  unsigned int* qdata = (unsigned int*)take((size_t)24 * QCAP * 4);
  float* dinv = (float*)take(NN * 4);
  float* Binv = (float*)take(NN * 4);
  float* Dninv = (float*)take(NN * 4);
  float4* simbuf = (float4*)take((size_t)NN * 16);
  unsigned short* Wpack = (unsigned short*)take((size_t)7 * 16384 * 2);
  const size_t BFSZ = (size_t)NN * HH * 2;
  unsigned short* B2 = (unsigned short*)take(BFSZ);
  unsigned short* B3 = (unsigned short*)take(BFSZ);
  unsigned short* B4 = (unsigned short*)take(BFSZ);
  unsigned short* B5 = (unsigned short*)take(BFSZ);
  unsigned short* B6 = (unsigned short*)take(BFSZ);  // feats2 bf16
  unsigned char* P1 = (unsigned char*)take((size_t)NN * 256);  // fp8 pair [node][2][128]
  unsigned char* P2 = (unsigned char*)take((size_t)NN * 256);
  unsigned char* P3 = (unsigned char*)take((size_t)NN * 256);

  const int GMB = (NN + 63) / 64;    // gemm blocks (64 rows each)
  const int GTB = (NN + 7) / 8;      // gather blocks (8 nodes/block, 32 lanes/node)
  const int RB = (NN + 3) / 4;       // row-wave blocks
  const short8* Wp = (const short8*)Wpack;

  hipMemsetAsync(d_ws, 0, zero_end, stream);
  pack_k<<<(7 * 2048 + 255) / 256, 256, 0, stream>>>(W0, Wh0, Wlf, Wf0, Wfh0, Wm1, Wm2,
                                                     Wpack);
  // radix fill: bin once, then LDS-cursor fill (+derive +s_hq counts; no edge re-scan)
  bin_k<<<BINB, 256, 0, stream>>>(ei, ea, qcnt, qdata, pos, qp, maskI);
  fillp_k<<<24 * WSUB, 256, 0, stream>>>(qcnt, qdata, cursor3, slotsA, slotsB, slotsC,
                                         cntq, qp, dinv, Binv, Dninv, s_hq);
  // feats @ {W0, Wh0, Wlf}: xw0 -> P1.half0 (fp8), xwh -> P2.half0 (fp8), feats2 -> B6 bf16
  gemm3_mfma<<<2 * GMB, 256, 0, stream>>>(feats, Wp, blf, P1, P2, B6, NN);
  // fuse2 -> B3=hf_, B4=hfh_
  fuse2_k<<<RB, 256, 0, stream>>>(B6, qp, Wlq, blq, aq_, a_, ahq_, ah_, B3, B4);
  // xwf -> P1.half1 ; xwfh -> P2.half1  (fp8, batched)
  gemm2_mfma<false, false, 2><<<2 * GMB, 256, 0, stream>>>(
      B3, B4, Wp + (size_t)3 * 2048, Wp + (size_t)4 * 2048, nullptr, nullptr, P1 + 128,
      P2 + 128, NN, GMB);
  // gathers: pass1 GCN P1 -> fused epilogue -> B3=hf ; pass2 HG-he P2 -> P3 fp8 [merged]
  dgather12_k<<<2 * GTB, 256, 0, stream>>>((const uint2*)P1, B3, (const uint2*)P2,
                                           (uint2*)P3, cursor3, slotsA, slotsB, dinv, Binv,
                                           s_hq, qp, Wq0, bq0, b0, aq0, a0, bf0, GTB);
  // pass3 HG-node P3 -> fused epilogue (inline s_hgq) -> B4=h_augf
  dgather3_k<<<GTB, 256, 0, stream>>>((const uint2*)P3, B4, cursor3, slotsC, Dninv, Binv,
                                      cntq, Whq0, bhq0, bh0, ahq0, ah0, bfh0);
  // fused 2-layer MLP: B3 -> B2=z, B4 -> B5=z_aug
  gemm22_mfma<<<2 * GMB, 256, 0, stream>>>(B3, B4, Wp + (size_t)5 * 2048,
                                           Wp + (size_t)6 * 2048, bm1, bm2, B2, B5, NN,
                                           GMB);
  // loss
  sim_k<<<RB, 256, 0, stream>>>(B2, B5, qp, simbuf, scal);
  reduce_sim_k<<<64, 256, 0, stream>>>(simbuf, maskI, scal);
  final_k<<<1, 64, 0, stream>>>(scal, (float*)d_out);
}